// Round 1
// baseline (385.790 us; speedup 1.0000x reference)
//
#include <hip/hip_runtime.h>
#include <hip/hip_bf16.h>

#define NF 128

// ---------------- zero scratch ----------------
__global__ __launch_bounds__(256) void k_zero(int* __restrict__ p, int nwords) {
    int i = blockIdx.x * 256 + threadIdx.x;
    if (i < nwords) p[i] = 0;
}

// ---------------- degree count ----------------
__global__ __launch_bounds__(256) void k_deg(const int* __restrict__ ei, int E,
                                             int* __restrict__ deg) {
    int i = blockIdx.x * 256 + threadIdx.x;
    if (i < E) atomicAdd(&deg[ei[E + i]], 1);
}

// ---------------- 3-kernel deterministic exclusive scan over deg ----------------
__global__ __launch_bounds__(256) void k_scanA(const int* __restrict__ deg, int N,
                                               int* __restrict__ bsum) {
    __shared__ int red[256];
    int tid = threadIdx.x;
    int i = blockIdx.x * 256 + tid;
    int v = (i < N) ? deg[i] : 0;
    red[tid] = v; __syncthreads();
    for (int s = 128; s > 0; s >>= 1) {
        if (tid < s) red[tid] += red[tid + s];
        __syncthreads();
    }
    if (tid == 0) bsum[blockIdx.x] = red[0];
}

__global__ __launch_bounds__(256) void k_scanB(const int* __restrict__ bsum, int NB,
                                               int* __restrict__ bbase) {
    __shared__ int sc[256];
    int tid = threadIdx.x;
    int v = (tid < NB) ? bsum[tid] : 0;
    sc[tid] = v; __syncthreads();
    for (int s = 1; s < 256; s <<= 1) {
        int t = (tid >= s) ? sc[tid - s] : 0;
        __syncthreads();
        sc[tid] += t;
        __syncthreads();
    }
    bbase[tid] = sc[tid] - v;   // exclusive
}

__global__ __launch_bounds__(256) void k_scanC(const int* __restrict__ deg, int N,
                                               const int* __restrict__ bbase,
                                               int* __restrict__ offs,
                                               float* __restrict__ invd) {
    __shared__ int sc[256];
    int tid = threadIdx.x;
    int i = blockIdx.x * 256 + tid;
    int v = (i < N) ? deg[i] : 0;
    sc[tid] = v; __syncthreads();
    for (int s = 1; s < 256; s <<= 1) {
        int t = (tid >= s) ? sc[tid - s] : 0;
        __syncthreads();
        sc[tid] += t;
        __syncthreads();
    }
    if (i < N) {
        offs[i] = bbase[blockIdx.x] + sc[tid] - v;
        invd[i] = (v > 0) ? 1.0f / (float)v : 0.0f;
    }
}

// ---------------- CSR fill ----------------
__global__ __launch_bounds__(256) void k_fill(const int* __restrict__ ei, int E,
                                              const int* __restrict__ offs,
                                              int* __restrict__ cursor,
                                              int* __restrict__ csr) {
    int i = blockIdx.x * 256 + threadIdx.x;
    if (i < E) {
        int d = ei[E + i];
        int p = atomicAdd(&cursor[d], 1);
        csr[offs[d] + p] = ei[i];
    }
}

// ---------------- weight pre-transpose+swizzle: wprep[mat][k][cq'] (float4) ----------------
// logical element (k, f) with f = fg*16 + i*4 + j stored at quad cq' = i*8 + fg
__global__ __launch_bounds__(256) void k_prep_w(const float* __restrict__ w0,
                                                const float* __restrict__ w1,
                                                const float* __restrict__ w2,
                                                const float* __restrict__ w3,
                                                float4* __restrict__ wprep) {
    int flat = blockIdx.x * 256 + threadIdx.x;   // 0..16383
    const float* W = (flat < 4096) ? w0 : (flat < 8192) ? w1 : (flat < 12288) ? w2 : w3;
    int rem = flat & 4095;
    int k = rem >> 5, cq = rem & 31;
    int fg = cq & 7, ii = cq >> 3;
    int f = fg * 16 + ii * 4;
    float4 v;
    v.x = W[(f + 0) * NF + k];
    v.y = W[(f + 1) * NF + k];
    v.z = W[(f + 2) * NF + k];
    v.w = W[(f + 3) * NF + k];
    wprep[flat] = v;
}

// ---------------- aggregate: one wave per node ----------------
template <bool TR>
__global__ __launch_bounds__(256) void k_agg(const float2* __restrict__ in2,
                                             const int* __restrict__ csr,
                                             const int* __restrict__ offs,
                                             const int* __restrict__ deg,
                                             const float* __restrict__ invd,
                                             const float* __restrict__ sbn,
                                             const float* __restrict__ bbn,
                                             float2* __restrict__ out2, int N) {
    int wid = threadIdx.x >> 6, lane = threadIdx.x & 63;
    int node = blockIdx.x * 4 + wid;
    if (node >= N) return;
    int beg = offs[node], cnt = deg[node];
    float a0x = 0, a0y = 0, a1x = 0, a1y = 0, a2x = 0, a2y = 0, a3x = 0, a3y = 0;
    int j = 0;
    for (; j + 4 <= cnt; j += 4) {
        int s0 = csr[beg + j + 0], s1 = csr[beg + j + 1];
        int s2 = csr[beg + j + 2], s3 = csr[beg + j + 3];
        float2 v0 = in2[(size_t)s0 * 64 + lane];
        float2 v1 = in2[(size_t)s1 * 64 + lane];
        float2 v2 = in2[(size_t)s2 * 64 + lane];
        float2 v3 = in2[(size_t)s3 * 64 + lane];
        a0x += v0.x; a0y += v0.y; a1x += v1.x; a1y += v1.y;
        a2x += v2.x; a2y += v2.y; a3x += v3.x; a3y += v3.y;
    }
    for (; j < cnt; ++j) {
        int s = csr[beg + j];
        float2 v = in2[(size_t)s * 64 + lane];
        a0x += v.x; a0y += v.y;
    }
    float id = invd[node];
    float rx = ((a0x + a1x) + (a2x + a3x)) * id;
    float ry = ((a0y + a1y) + (a2y + a3y)) * id;
    if (TR) {
        if (cnt > 0) {   // mean(s*v+b) = s*mean(v)+b when deg>0, else 0
            float2 s2 = ((const float2*)sbn)[lane];
            float2 b2 = ((const float2*)bbn)[lane];
            rx = rx * s2.x + b2.x;
            ry = ry * s2.y + b2.y;
        }
    }
    out2[(size_t)node * 64 + lane] = make_float2(rx, ry);
}

// ---------------- fused linear (+bias +L2norm) ; MODE1: relu+BN stats, MODE2: fused FC ----
template <int MODE>
__global__ __launch_bounds__(256, 2) void k_lin(
    const float4* __restrict__ aggIn4,   // [N][32]
    const float4* __restrict__ xIn4,     // [N][32]
    const float4* __restrict__ wprep,    // [2][128][32] quads for this layer
    const float* __restrict__ bias,      // [128]
    const float4* __restrict__ sbn4, const float4* __restrict__ bbn4,  // MODE2
    const float* __restrict__ wfc, const float* __restrict__ bfc,      // MODE2
    float* __restrict__ outp,            // MODE1: h1r [N,128]; MODE2: out [N,8]
    float* __restrict__ bnSum, float* __restrict__ bnSq, int N) {
    __shared__ float4 ws4[64 * 32];     // 32 KB (half-K)
    __shared__ float As[32 * 132];      // 16.9 KB
    __shared__ float wfcs[8 * NF];      // 4 KB
    __shared__ float bns[2][NF];        // 1 KB

    int tid = threadIdx.x;
    int r = tid >> 3, fg = tid & 7;
    int row0 = blockIdx.x * 32;
    int row = row0 + r;
    bool valid = row < N;

    if constexpr (MODE == 1) {
        if (tid < 128) { bns[0][tid] = 0.f; bns[1][tid] = 0.f; }
    }
    if constexpr (MODE == 2) {
#pragma unroll
        for (int it = 0; it < 4; ++it) wfcs[tid + it * 256] = wfc[tid + it * 256];
    }

    float acc[16];
#pragma unroll
    for (int i = 0; i < 16; i++) acc[i] = 0.f;

    for (int pass = 0; pass < 2; ++pass) {
        // stage A tile (32 rows x 128)
        const float4* a4 = (pass == 0) ? aggIn4 : xIn4;
#pragma unroll
        for (int it = 0; it < 4; ++it) {
            int idx = tid + it * 256;            // 0..1023
            int ar = idx >> 5, c4 = idx & 31;
            int arow = row0 + ar;
            float4 v = a4[(size_t)(arow < N ? arow : 0) * 32 + c4];
            if constexpr (MODE == 2) {
                if (pass == 1) {
                    float4 s = sbn4[c4], b = bbn4[c4];
                    v.x = v.x * s.x + b.x; v.y = v.y * s.y + b.y;
                    v.z = v.z * s.z + b.z; v.w = v.w * s.w + b.w;
                }
            }
            *(float4*)&As[ar * 132 + c4 * 4] = v;
        }
        for (int half = 0; half < 2; ++half) {
            const float4* wsrc = wprep + pass * 4096 + half * 2048;
#pragma unroll
            for (int it = 0; it < 8; ++it) ws4[tid + it * 256] = wsrc[tid + it * 256];
            __syncthreads();
            int kbase = half * 64;
#pragma unroll 4
            for (int k = 0; k < 64; k++) {
                float a = As[r * 132 + kbase + k];
                const float4* wr = &ws4[k * 32 + fg];
#pragma unroll
                for (int i = 0; i < 4; i++) {
                    float4 w = wr[i * 8];
                    acc[i * 4 + 0] += a * w.x;
                    acc[i * 4 + 1] += a * w.y;
                    acc[i * 4 + 2] += a * w.z;
                    acc[i * 4 + 3] += a * w.w;
                }
            }
            __syncthreads();
        }
    }

    // bias
    {
        const float4* b4 = (const float4*)bias;
#pragma unroll
        for (int i = 0; i < 4; i++) {
            float4 b = b4[fg * 4 + i];
            acc[i * 4 + 0] += b.x; acc[i * 4 + 1] += b.y;
            acc[i * 4 + 2] += b.z; acc[i * 4 + 3] += b.w;
        }
    }
    // row L2 norm (8 lanes per row, fg = lane bits 0..2)
    float ss = 0.f;
#pragma unroll
    for (int i = 0; i < 16; i++) ss += acc[i] * acc[i];
    ss += __shfl_xor(ss, 1); ss += __shfl_xor(ss, 2); ss += __shfl_xor(ss, 4);
    float inv = 1.0f / fmaxf(sqrtf(ss), 1e-12f);
#pragma unroll
    for (int i = 0; i < 16; i++) acc[i] *= inv;

    if constexpr (MODE == 1) {
        float su[16], sq[16];
#pragma unroll
        for (int i = 0; i < 16; i++) {
            float u = fmaxf(acc[i], 0.f);
            acc[i] = u;
            u = valid ? u : 0.f;
            su[i] = u; sq[i] = u * u;
        }
        // reduce over the 8 rows within the wave (lane bits 3..5)
#pragma unroll
        for (int m = 8; m <= 32; m <<= 1) {
#pragma unroll
            for (int i = 0; i < 16; i++) {
                su[i] += __shfl_xor(su[i], m);
                sq[i] += __shfl_xor(sq[i], m);
            }
        }
        int lane = tid & 63;
        if (lane < 8) {
#pragma unroll
            for (int i = 0; i < 16; i++) {
                atomicAdd(&bns[0][fg * 16 + i], su[i]);
                atomicAdd(&bns[1][fg * 16 + i], sq[i]);
            }
        }
        if (valid) {
            float4* o4 = (float4*)(outp + (size_t)row * NF + fg * 16);
#pragma unroll
            for (int i = 0; i < 4; i++)
                o4[i] = make_float4(acc[i * 4], acc[i * 4 + 1], acc[i * 4 + 2], acc[i * 4 + 3]);
        }
        __syncthreads();
        if (tid < 128) atomicAdd(&bnSum[tid], bns[0][tid]);
        else           atomicAdd(&bnSq[tid - 128], bns[1][tid - 128]);
    } else {
        float o[8];
#pragma unroll
        for (int c = 0; c < 8; c++) {
            float t = 0.f;
#pragma unroll
            for (int i = 0; i < 16; i++) t += acc[i] * wfcs[c * NF + fg * 16 + i];
            o[c] = t;
        }
#pragma unroll
        for (int c = 0; c < 8; c++) {
            o[c] += __shfl_xor(o[c], 1);
            o[c] += __shfl_xor(o[c], 2);
            o[c] += __shfl_xor(o[c], 4);
        }
        if (fg == 0 && valid) {
#pragma unroll
            for (int c = 0; c < 8; c++) outp[(size_t)row * 8 + c] = o[c] + bfc[c];
        }
    }
}

// ---------------- BN finalize: fold to scale/shift ----------------
__global__ void k_bnfin(const float* __restrict__ bnSum, const float* __restrict__ bnSq,
                        const float* __restrict__ gamma, const float* __restrict__ beta,
                        float* __restrict__ sbn, float* __restrict__ bbn, float n) {
    int f = threadIdx.x;
    float mu = bnSum[f] / n;
    float var = bnSq[f] / n - mu * mu;
    var = fmaxf(var, 0.f);
    float s = gamma[f] / sqrtf(var + 1e-5f);
    sbn[f] = s;
    bbn[f] = beta[f] - mu * s;
}

extern "C" void kernel_launch(void* const* d_in, const int* in_sizes, int n_in,
                              void* d_out, int out_size, void* d_ws, size_t ws_size,
                              hipStream_t stream) {
    const float* x   = (const float*)d_in[0];
    const int*   ei  = (const int*)d_in[1];
    const float* W1l = (const float*)d_in[2];
    const float* b1l = (const float*)d_in[3];
    const float* W1r = (const float*)d_in[4];
    const float* gam = (const float*)d_in[5];
    const float* bet = (const float*)d_in[6];
    const float* W2l = (const float*)d_in[7];
    const float* b2l = (const float*)d_in[8];
    const float* W2r = (const float*)d_in[9];
    const float* Wfc = (const float*)d_in[10];
    const float* bfc = (const float*)d_in[11];
    int N = in_sizes[0] / NF;
    int E = in_sizes[1] / 2;

    char* w = (char*)d_ws;
    size_t o = 0;
    int* deg    = (int*)(w + o); o += (size_t)N * 4;
    int* cursor = (int*)(w + o); o += (size_t)N * 4;
    float* bnSum = (float*)(w + o); o += 512;
    float* bnSq  = (float*)(w + o); o += 512;
    size_t zwords = o / 4;                     // zero region: deg, cursor, bn accum
    int* offs  = (int*)(w + o); o += (size_t)N * 4;
    float* invd = (float*)(w + o); o += (size_t)N * 4;
    int* bsum  = (int*)(w + o); o += 1024;
    int* bbase = (int*)(w + o); o += 1024;
    int* csr   = (int*)(w + o); o += (size_t)E * 4;
    float4* wprep = (float4*)(w + o); o += (size_t)4 * 128 * 32 * 16;
    float* sbn = (float*)(w + o); o += 512;
    float* bbn = (float*)(w + o); o += 512;
    float* agg = (float*)(w + o); o += (size_t)N * NF * 4;
    float* h1r = (float*)(w + o); o += (size_t)N * NF * 4;
    (void)ws_size; (void)n_in; (void)out_size;

    int NB = (N + 255) / 256;
    int EB = (E + 255) / 256;
    int nodeBlocks = (N + 3) / 4;
    int MB = (N + 31) / 32;

    k_zero<<<(int)((zwords + 255) / 256), 256, 0, stream>>>((int*)d_ws, (int)zwords);
    k_deg<<<EB, 256, 0, stream>>>(ei, E, deg);
    k_prep_w<<<64, 256, 0, stream>>>(W1l, W1r, W2l, W2r, wprep);
    k_scanA<<<NB, 256, 0, stream>>>(deg, N, bsum);
    k_scanB<<<1, 256, 0, stream>>>(bsum, NB, bbase);
    k_scanC<<<NB, 256, 0, stream>>>(deg, N, bbase, offs, invd);
    k_fill<<<EB, 256, 0, stream>>>(ei, E, offs, cursor, csr);

    // layer 1
    k_agg<false><<<nodeBlocks, 256, 0, stream>>>((const float2*)x, csr, offs, deg, invd,
                                                 nullptr, nullptr, (float2*)agg, N);
    k_lin<1><<<MB, 256, 0, stream>>>((const float4*)agg, (const float4*)x, wprep, b1l,
                                     nullptr, nullptr, nullptr, nullptr,
                                     h1r, bnSum, bnSq, N);
    k_bnfin<<<1, 128, 0, stream>>>(bnSum, bnSq, gam, bet, sbn, bbn, (float)N);
    // layer 2 (BN folded into aggregate epilogue / lin_r staging) + fused FC head
    k_agg<true><<<nodeBlocks, 256, 0, stream>>>((const float2*)h1r, csr, offs, deg, invd,
                                                sbn, bbn, (float2*)agg, N);
    k_lin<2><<<MB, 256, 0, stream>>>((const float4*)agg, (const float4*)h1r, wprep + 2 * 4096,
                                     b2l, (const float4*)sbn, (const float4*)bbn, Wfc, bfc,
                                     (float*)d_out, nullptr, nullptr, N);
}

// Round 2
// 367.161 us; speedup vs baseline: 1.0507x; 1.0507x over previous
//
#include <hip/hip_runtime.h>
#include <hip/hip_bf16.h>

#define NF 128

// ---------------- zero scratch ----------------
__global__ __launch_bounds__(256) void k_zero(int* __restrict__ p, int nwords) {
    int i = blockIdx.x * 256 + threadIdx.x;
    if (i < nwords) p[i] = 0;
}

// ---------------- degree count ----------------
__global__ __launch_bounds__(256) void k_deg(const int* __restrict__ ei, int E,
                                             int* __restrict__ deg) {
    int i = blockIdx.x * 256 + threadIdx.x;
    if (i < E) atomicAdd(&deg[ei[E + i]], 1);
}

// ---------------- 3-kernel deterministic exclusive scan over deg ----------------
__global__ __launch_bounds__(256) void k_scanA(const int* __restrict__ deg, int N,
                                               int* __restrict__ bsum) {
    __shared__ int red[256];
    int tid = threadIdx.x;
    int i = blockIdx.x * 256 + tid;
    int v = (i < N) ? deg[i] : 0;
    red[tid] = v; __syncthreads();
    for (int s = 128; s > 0; s >>= 1) {
        if (tid < s) red[tid] += red[tid + s];
        __syncthreads();
    }
    if (tid == 0) bsum[blockIdx.x] = red[0];
}

__global__ __launch_bounds__(256) void k_scanB(const int* __restrict__ bsum, int NB,
                                               int* __restrict__ bbase) {
    __shared__ int sc[256];
    int tid = threadIdx.x;
    int v = (tid < NB) ? bsum[tid] : 0;
    sc[tid] = v; __syncthreads();
    for (int s = 1; s < 256; s <<= 1) {
        int t = (tid >= s) ? sc[tid - s] : 0;
        __syncthreads();
        sc[tid] += t;
        __syncthreads();
    }
    bbase[tid] = sc[tid] - v;   // exclusive
}

__global__ __launch_bounds__(256) void k_scanC(const int* __restrict__ deg, int N,
                                               const int* __restrict__ bbase,
                                               int* __restrict__ offs,
                                               float* __restrict__ invd) {
    __shared__ int sc[256];
    int tid = threadIdx.x;
    int i = blockIdx.x * 256 + tid;
    int v = (i < N) ? deg[i] : 0;
    sc[tid] = v; __syncthreads();
    for (int s = 1; s < 256; s <<= 1) {
        int t = (tid >= s) ? sc[tid - s] : 0;
        __syncthreads();
        sc[tid] += t;
        __syncthreads();
    }
    if (i < N) {
        offs[i] = bbase[blockIdx.x] + sc[tid] - v;
        invd[i] = (v > 0) ? 1.0f / (float)v : 0.0f;
    }
}

// ---------------- CSR fill ----------------
__global__ __launch_bounds__(256) void k_fill(const int* __restrict__ ei, int E,
                                              const int* __restrict__ offs,
                                              int* __restrict__ cursor,
                                              int* __restrict__ csr) {
    int i = blockIdx.x * 256 + threadIdx.x;
    if (i < E) {
        int d = ei[E + i];
        int p = atomicAdd(&cursor[d], 1);
        csr[offs[d] + p] = ei[i];
    }
}

// ---------------- weight pre-transpose+swizzle: wprep[mat][k][cq'] (float4) ----------------
// logical element (k, f) with f = fg*16 + i*4 + j stored at quad cq' = i*8 + fg
__global__ __launch_bounds__(256) void k_prep_w(const float* __restrict__ w0,
                                                const float* __restrict__ w1,
                                                const float* __restrict__ w2,
                                                const float* __restrict__ w3,
                                                float4* __restrict__ wprep) {
    int flat = blockIdx.x * 256 + threadIdx.x;   // 0..16383
    const float* W = (flat < 4096) ? w0 : (flat < 8192) ? w1 : (flat < 12288) ? w2 : w3;
    int rem = flat & 4095;
    int k = rem >> 5, cq = rem & 31;
    int fg = cq & 7, ii = cq >> 3;
    int f = fg * 16 + ii * 4;
    float4 v;
    v.x = W[(f + 0) * NF + k];
    v.y = W[(f + 1) * NF + k];
    v.z = W[(f + 2) * NF + k];
    v.w = W[(f + 3) * NF + k];
    wprep[flat] = v;
}

// ---------------- aggregate: one wave per node ----------------
template <bool TR>
__global__ __launch_bounds__(256) void k_agg(const float2* __restrict__ in2,
                                             const int* __restrict__ csr,
                                             const int* __restrict__ offs,
                                             const int* __restrict__ deg,
                                             const float* __restrict__ invd,
                                             const float* __restrict__ sbn,
                                             const float* __restrict__ bbn,
                                             float2* __restrict__ out2, int N) {
    int wid = threadIdx.x >> 6, lane = threadIdx.x & 63;
    int node = blockIdx.x * 4 + wid;
    if (node >= N) return;
    int beg = offs[node], cnt = deg[node];
    float a0x = 0, a0y = 0, a1x = 0, a1y = 0, a2x = 0, a2y = 0, a3x = 0, a3y = 0;
    int j = 0;
    for (; j + 4 <= cnt; j += 4) {
        int s0 = csr[beg + j + 0], s1 = csr[beg + j + 1];
        int s2 = csr[beg + j + 2], s3 = csr[beg + j + 3];
        float2 v0 = in2[(size_t)s0 * 64 + lane];
        float2 v1 = in2[(size_t)s1 * 64 + lane];
        float2 v2 = in2[(size_t)s2 * 64 + lane];
        float2 v3 = in2[(size_t)s3 * 64 + lane];
        a0x += v0.x; a0y += v0.y; a1x += v1.x; a1y += v1.y;
        a2x += v2.x; a2y += v2.y; a3x += v3.x; a3y += v3.y;
    }
    for (; j < cnt; ++j) {
        int s = csr[beg + j];
        float2 v = in2[(size_t)s * 64 + lane];
        a0x += v.x; a0y += v.y;
    }
    float id = invd[node];
    float rx = ((a0x + a1x) + (a2x + a3x)) * id;
    float ry = ((a0y + a1y) + (a2y + a3y)) * id;
    if (TR) {
        if (cnt > 0) {   // mean(s*v+b) = s*mean(v)+b when deg>0, else 0
            float2 s2 = ((const float2*)sbn)[lane];
            float2 b2 = ((const float2*)bbn)[lane];
            rx = rx * s2.x + b2.x;
            ry = ry * s2.y + b2.y;
        }
    }
    out2[(size_t)node * 64 + lane] = make_float2(rx, ry);
}

// ---------------- fused linear (+bias +L2norm) ----------------
// 128 rows x 128 cols per block; thread = 4 rows (rg) x 16 cols (fg).
// K=256 = [agg 128 | x 128], chunks of 32. LDS: ws4 16KB + As 18.5KB = 34.5KB.
// As stride 37: bank(row) = 5*row mod 32 -> 8 wave-rows hit 8 distinct banks.
template <int MODE>
__global__ __launch_bounds__(256, 4) void k_lin(
    const float4* __restrict__ aggIn4,   // [N][32]
    const float4* __restrict__ xIn4,     // [N][32]
    const float4* __restrict__ wprep,    // [2][128][32] quads for this layer
    const float* __restrict__ bias,      // [128]
    const float4* __restrict__ sbn4, const float4* __restrict__ bbn4,  // MODE2
    const float* __restrict__ wfc, const float* __restrict__ bfc,      // MODE2
    float* __restrict__ outp,            // MODE1: h1r [N,128]; MODE2: out [N,8]
    float* __restrict__ bnSum, float* __restrict__ bnSq, int N) {
    __shared__ float4 ws4[32 * 32];      // 16 KB: 32 k x 32 quads (swizzled cols)
    __shared__ float As[128 * 37];       // 18.5 KB

    int tid = threadIdx.x;
    int fg = tid & 7;          // col group: cols fg*16 .. fg*16+15
    int rg = tid >> 3;         // row group: rows rg*4 .. rg*4+3
    int row0 = blockIdx.x * 128;
    int lane = tid & 63;

    float acc[64];
#pragma unroll
    for (int i = 0; i < 64; i++) acc[i] = 0.f;

#pragma unroll 1
    for (int chunk = 0; chunk < 8; ++chunk) {
        const float4* a4 = (chunk < 4) ? aggIn4 : xIn4;
        int kb = (chunk & 3) * 8;    // quad offset within source row
        const float4* wsrc = wprep + (chunk >> 2) * 4096 + (chunk & 3) * 1024;
#pragma unroll
        for (int it = 0; it < 4; ++it) {
            int idx = tid + it * 256;            // 0..1023 = 128 rows x 8 quads
            int r = idx >> 3, q = idx & 7;
            int arow = row0 + r;
            float4 v = a4[(size_t)(arow < N ? arow : 0) * 32 + kb + q];
            if constexpr (MODE == 2) {
                if (chunk >= 4) {                // BN fold on lin_r input
                    float4 s = sbn4[(chunk - 4) * 8 + q];
                    float4 b = bbn4[(chunk - 4) * 8 + q];
                    v.x = v.x * s.x + b.x; v.y = v.y * s.y + b.y;
                    v.z = v.z * s.z + b.z; v.w = v.w * s.w + b.w;
                }
            }
            float* dst = &As[r * 37 + q * 4];    // scalar writes (stride 37, <=2-way)
            dst[0] = v.x; dst[1] = v.y; dst[2] = v.z; dst[3] = v.w;
            ws4[idx] = wsrc[idx];
        }
        __syncthreads();
        int b0 = (rg * 4) * 37, b1 = b0 + 37, b2 = b1 + 37, b3 = b2 + 37;
#pragma unroll 4
        for (int k = 0; k < 32; ++k) {
            float a0 = As[b0 + k], a1 = As[b1 + k], a2 = As[b2 + k], a3 = As[b3 + k];
#pragma unroll
            for (int i = 0; i < 4; ++i) {
                float4 w = ws4[k * 32 + i * 8 + fg];
                acc[ 0 + i * 4 + 0] += a0 * w.x; acc[ 0 + i * 4 + 1] += a0 * w.y;
                acc[ 0 + i * 4 + 2] += a0 * w.z; acc[ 0 + i * 4 + 3] += a0 * w.w;
                acc[16 + i * 4 + 0] += a1 * w.x; acc[16 + i * 4 + 1] += a1 * w.y;
                acc[16 + i * 4 + 2] += a1 * w.z; acc[16 + i * 4 + 3] += a1 * w.w;
                acc[32 + i * 4 + 0] += a2 * w.x; acc[32 + i * 4 + 1] += a2 * w.y;
                acc[32 + i * 4 + 2] += a2 * w.z; acc[32 + i * 4 + 3] += a2 * w.w;
                acc[48 + i * 4 + 0] += a3 * w.x; acc[48 + i * 4 + 1] += a3 * w.y;
                acc[48 + i * 4 + 2] += a3 * w.z; acc[48 + i * 4 + 3] += a3 * w.w;
            }
        }
        __syncthreads();
    }

    // bias
#pragma unroll
    for (int i = 0; i < 4; ++i) {
        float4 b = ((const float4*)bias)[fg * 4 + i];
#pragma unroll
        for (int j = 0; j < 4; ++j) {
            acc[j * 16 + i * 4 + 0] += b.x; acc[j * 16 + i * 4 + 1] += b.y;
            acc[j * 16 + i * 4 + 2] += b.z; acc[j * 16 + i * 4 + 3] += b.w;
        }
    }
    // row L2 norm (8 lanes per row share it: lane bits 0..2 = fg)
#pragma unroll
    for (int j = 0; j < 4; ++j) {
        float ss = 0.f;
#pragma unroll
        for (int i = 0; i < 16; i++) ss += acc[j * 16 + i] * acc[j * 16 + i];
        ss += __shfl_xor(ss, 1); ss += __shfl_xor(ss, 2); ss += __shfl_xor(ss, 4);
        float inv = 1.0f / fmaxf(sqrtf(ss), 1e-12f);
#pragma unroll
        for (int i = 0; i < 16; i++) acc[j * 16 + i] *= inv;
    }

    if constexpr (MODE == 1) {
        float* bns = (float*)ws4;        // alias: main loop done
        if (tid < 128) { bns[tid] = 0.f; bns[tid + 128] = 0.f; }
        __syncthreads();
        // relu in place
#pragma unroll
        for (int i = 0; i < 64; i++) acc[i] = fmaxf(acc[i], 0.f);
        // per-col partial sums over this block's 128 rows (two halves of 8 cols
        // to cap register pressure)
#pragma unroll
        for (int h = 0; h < 2; ++h) {
            float su[8], sq[8];
#pragma unroll
            for (int i = 0; i < 8; i++) { su[i] = 0.f; sq[i] = 0.f; }
#pragma unroll
            for (int j = 0; j < 4; ++j) {
                bool vj = (row0 + rg * 4 + j) < N;
#pragma unroll
                for (int i = 0; i < 8; i++) {
                    float u = vj ? acc[j * 16 + h * 8 + i] : 0.f;
                    su[i] += u; sq[i] += u * u;
                }
            }
#pragma unroll
            for (int m = 8; m <= 32; m <<= 1) {
#pragma unroll
                for (int i = 0; i < 8; i++) {
                    su[i] += __shfl_xor(su[i], m);
                    sq[i] += __shfl_xor(sq[i], m);
                }
            }
            if (lane < 8) {
#pragma unroll
                for (int i = 0; i < 8; i++) {
                    atomicAdd(&bns[fg * 16 + h * 8 + i], su[i]);
                    atomicAdd(&bns[128 + fg * 16 + h * 8 + i], sq[i]);
                }
            }
        }
        // store h1r
#pragma unroll
        for (int j = 0; j < 4; ++j) {
            int row = row0 + rg * 4 + j;
            if (row < N) {
                float4* o4 = (float4*)(outp + (size_t)row * NF + fg * 16);
#pragma unroll
                for (int i = 0; i < 4; i++)
                    o4[i] = make_float4(acc[j * 16 + i * 4], acc[j * 16 + i * 4 + 1],
                                        acc[j * 16 + i * 4 + 2], acc[j * 16 + i * 4 + 3]);
            }
        }
        __syncthreads();
        if (tid < 128) atomicAdd(&bnSum[tid], bns[tid]);
        else           atomicAdd(&bnSq[tid - 128], bns[tid]);
    } else {
        float* wfcs = (float*)ws4;       // alias: 8 x 128 FC weights
#pragma unroll
        for (int it = 0; it < 4; ++it) wfcs[tid + it * 256] = wfc[tid + it * 256];
        __syncthreads();
        const float4* wf4 = (const float4*)wfcs;
#pragma unroll
        for (int j = 0; j < 4; ++j) {
            int row = row0 + rg * 4 + j;
            float o[8];
#pragma unroll
            for (int c = 0; c < 8; c++) {
                float t = 0.f;
#pragma unroll
                for (int i = 0; i < 4; i++) {
                    float4 w = wf4[c * 32 + fg * 4 + i];
                    t += acc[j * 16 + i * 4 + 0] * w.x + acc[j * 16 + i * 4 + 1] * w.y +
                         acc[j * 16 + i * 4 + 2] * w.z + acc[j * 16 + i * 4 + 3] * w.w;
                }
                o[c] = t;
            }
#pragma unroll
            for (int c = 0; c < 8; c++) {
                o[c] += __shfl_xor(o[c], 1);
                o[c] += __shfl_xor(o[c], 2);
                o[c] += __shfl_xor(o[c], 4);
            }
            if (fg == 0 && row < N) {
#pragma unroll
                for (int c = 0; c < 8; c++) outp[(size_t)row * 8 + c] = o[c] + bfc[c];
            }
        }
    }
}

// ---------------- BN finalize: fold to scale/shift ----------------
__global__ void k_bnfin(const float* __restrict__ bnSum, const float* __restrict__ bnSq,
                        const float* __restrict__ gamma, const float* __restrict__ beta,
                        float* __restrict__ sbn, float* __restrict__ bbn, float n) {
    int f = threadIdx.x;
    float mu = bnSum[f] / n;
    float var = bnSq[f] / n - mu * mu;
    var = fmaxf(var, 0.f);
    float s = gamma[f] / sqrtf(var + 1e-5f);
    sbn[f] = s;
    bbn[f] = beta[f] - mu * s;
}

extern "C" void kernel_launch(void* const* d_in, const int* in_sizes, int n_in,
                              void* d_out, int out_size, void* d_ws, size_t ws_size,
                              hipStream_t stream) {
    const float* x   = (const float*)d_in[0];
    const int*   ei  = (const int*)d_in[1];
    const float* W1l = (const float*)d_in[2];
    const float* b1l = (const float*)d_in[3];
    const float* W1r = (const float*)d_in[4];
    const float* gam = (const float*)d_in[5];
    const float* bet = (const float*)d_in[6];
    const float* W2l = (const float*)d_in[7];
    const float* b2l = (const float*)d_in[8];
    const float* W2r = (const float*)d_in[9];
    const float* Wfc = (const float*)d_in[10];
    const float* bfc = (const float*)d_in[11];
    int N = in_sizes[0] / NF;
    int E = in_sizes[1] / 2;

    char* w = (char*)d_ws;
    size_t o = 0;
    int* deg    = (int*)(w + o); o += (size_t)N * 4;
    int* cursor = (int*)(w + o); o += (size_t)N * 4;
    float* bnSum = (float*)(w + o); o += 512;
    float* bnSq  = (float*)(w + o); o += 512;
    size_t zwords = o / 4;                     // zero region: deg, cursor, bn accum
    int* offs  = (int*)(w + o); o += (size_t)N * 4;
    float* invd = (float*)(w + o); o += (size_t)N * 4;
    int* bsum  = (int*)(w + o); o += 1024;
    int* bbase = (int*)(w + o); o += 1024;
    int* csr   = (int*)(w + o); o += (size_t)E * 4;
    float4* wprep = (float4*)(w + o); o += (size_t)4 * 128 * 32 * 16;
    float* sbn = (float*)(w + o); o += 512;
    float* bbn = (float*)(w + o); o += 512;
    float* agg = (float*)(w + o); o += (size_t)N * NF * 4;
    float* h1r = (float*)(w + o); o += (size_t)N * NF * 4;
    (void)ws_size; (void)n_in; (void)out_size;

    int NB = (N + 255) / 256;
    int EB = (E + 255) / 256;
    int nodeBlocks = (N + 3) / 4;
    int MB = (N + 127) / 128;

    k_zero<<<(int)((zwords + 255) / 256), 256, 0, stream>>>((int*)d_ws, (int)zwords);
    k_deg<<<EB, 256, 0, stream>>>(ei, E, deg);
    k_prep_w<<<64, 256, 0, stream>>>(W1l, W1r, W2l, W2r, wprep);
    k_scanA<<<NB, 256, 0, stream>>>(deg, N, bsum);
    k_scanB<<<1, 256, 0, stream>>>(bsum, NB, bbase);
    k_scanC<<<NB, 256, 0, stream>>>(deg, N, bbase, offs, invd);
    k_fill<<<EB, 256, 0, stream>>>(ei, E, offs, cursor, csr);

    // layer 1
    k_agg<false><<<nodeBlocks, 256, 0, stream>>>((const float2*)x, csr, offs, deg, invd,
                                                 nullptr, nullptr, (float2*)agg, N);
    k_lin<1><<<MB, 256, 0, stream>>>((const float4*)agg, (const float4*)x, wprep, b1l,
                                     nullptr, nullptr, nullptr, nullptr,
                                     h1r, bnSum, bnSq, N);
    k_bnfin<<<1, 128, 0, stream>>>(bnSum, bnSq, gam, bet, sbn, bbn, (float)N);
    // layer 2 (BN folded into aggregate epilogue / lin_r staging) + fused FC head
    k_agg<true><<<nodeBlocks, 256, 0, stream>>>((const float2*)h1r, csr, offs, deg, invd,
                                                sbn, bbn, (float2*)agg, N);
    k_lin<2><<<MB, 256, 0, stream>>>((const float4*)agg, (const float4*)h1r, wprep + 2 * 4096,
                                     b2l, (const float4*)sbn, (const float4*)bbn, Wfc, bfc,
                                     (float*)d_out, nullptr, nullptr, N);
}

// Round 4
// 321.123 us; speedup vs baseline: 1.2014x; 1.1434x over previous
//
#include <hip/hip_runtime.h>
#include <hip/hip_bf16.h>

#define NF 128

typedef float f4 __attribute__((ext_vector_type(4)));

static __device__ __forceinline__ unsigned short f2b(float f) {
    union { float f; unsigned u; } c; c.f = f;
    unsigned r = c.u + 0x7fffu + ((c.u >> 16) & 1u);
    return (unsigned short)(r >> 16);
}
static __device__ __forceinline__ float blo(unsigned v) { return __uint_as_float(v << 16); }
static __device__ __forceinline__ float bhi(unsigned v) { return __uint_as_float(v & 0xffff0000u); }

// ---------------- zero scratch ----------------
__global__ __launch_bounds__(256) void k_zero(int* __restrict__ p, int nwords) {
    int i = blockIdx.x * 256 + threadIdx.x;
    if (i < nwords) p[i] = 0;
}

// ---------------- x -> bf16 ----------------
__global__ __launch_bounds__(256) void k_cvt(const float4* __restrict__ in,
                                             ushort4* __restrict__ out, int nq) {
    int i = blockIdx.x * 256 + threadIdx.x;
    if (i < nq) {
        float4 v = in[i];
        ushort4 u;
        u.x = f2b(v.x); u.y = f2b(v.y); u.z = f2b(v.z); u.w = f2b(v.w);
        out[i] = u;
    }
}

// ---------------- degree count ----------------
__global__ __launch_bounds__(256) void k_deg(const int* __restrict__ ei, int E,
                                             int* __restrict__ deg) {
    int i = blockIdx.x * 256 + threadIdx.x;
    if (i < E) atomicAdd(&deg[ei[E + i]], 1);
}

// ---------------- 3-kernel deterministic exclusive scan over deg ----------------
__global__ __launch_bounds__(256) void k_scanA(const int* __restrict__ deg, int N,
                                               int* __restrict__ bsum) {
    __shared__ int red[256];
    int tid = threadIdx.x;
    int i = blockIdx.x * 256 + tid;
    int v = (i < N) ? deg[i] : 0;
    red[tid] = v; __syncthreads();
    for (int s = 128; s > 0; s >>= 1) {
        if (tid < s) red[tid] += red[tid + s];
        __syncthreads();
    }
    if (tid == 0) bsum[blockIdx.x] = red[0];
}

__global__ __launch_bounds__(256) void k_scanB(const int* __restrict__ bsum, int NB,
                                               int* __restrict__ bbase) {
    __shared__ int sc[256];
    int tid = threadIdx.x;
    int v = (tid < NB) ? bsum[tid] : 0;
    sc[tid] = v; __syncthreads();
    for (int s = 1; s < 256; s <<= 1) {
        int t = (tid >= s) ? sc[tid - s] : 0;
        __syncthreads();
        sc[tid] += t;
        __syncthreads();
    }
    bbase[tid] = sc[tid] - v;   // exclusive
}

__global__ __launch_bounds__(256) void k_scanC(const int* __restrict__ deg, int N,
                                               const int* __restrict__ bbase,
                                               int* __restrict__ offs,
                                               float* __restrict__ invd) {
    __shared__ int sc[256];
    int tid = threadIdx.x;
    int i = blockIdx.x * 256 + tid;
    int v = (i < N) ? deg[i] : 0;
    sc[tid] = v; __syncthreads();
    for (int s = 1; s < 256; s <<= 1) {
        int t = (tid >= s) ? sc[tid - s] : 0;
        __syncthreads();
        sc[tid] += t;
        __syncthreads();
    }
    if (i < N) {
        offs[i] = bbase[blockIdx.x] + sc[tid] - v;
        invd[i] = (v > 0) ? 1.0f / (float)v : 0.0f;
    }
}

// ---------------- CSR fill ----------------
__global__ __launch_bounds__(256) void k_fill(const int* __restrict__ ei, int E,
                                              const int* __restrict__ offs,
                                              int* __restrict__ cursor,
                                              int* __restrict__ csr) {
    int i = blockIdx.x * 256 + threadIdx.x;
    if (i < E) {
        int d = ei[E + i];
        int p = atomicAdd(&cursor[d], 1);
        csr[offs[d] + p] = ei[i];
    }
}

// ---------------- weight pre-transpose: wt[m][k][f] = W_m[f][k], m in {1l,1r,2l,2r} ----
__global__ __launch_bounds__(256) void k_prep_w(const float* __restrict__ w0,
                                                const float* __restrict__ w1,
                                                const float* __restrict__ w2,
                                                const float* __restrict__ w3,
                                                float4* __restrict__ wt) {
    int idx = blockIdx.x * 256 + threadIdx.x;   // 0..16383 (float4 units)
    const float* W = (idx < 4096) ? w0 : (idx < 8192) ? w1 : (idx < 12288) ? w2 : w3;
    int rem = idx & 4095;
    int k = rem >> 5, cq = rem & 31;           // k row, col-quad
    float4 v;
    v.x = W[(cq * 4 + 0) * NF + k];
    v.y = W[(cq * 4 + 1) * NF + k];
    v.z = W[(cq * 4 + 2) * NF + k];
    v.w = W[(cq * 4 + 3) * NF + k];
    wt[idx] = v;
}

// ---------------- aggregate (bf16 gather, f32 accum): one wave per node ----------------
template <bool TR>
__global__ __launch_bounds__(256) void k_agg(const unsigned int* __restrict__ inb,
                                             const int* __restrict__ csr,
                                             const int* __restrict__ offs,
                                             const int* __restrict__ deg,
                                             const float* __restrict__ invd,
                                             const float* __restrict__ sbn,
                                             const float* __restrict__ bbn,
                                             float2* __restrict__ out2, int N) {
    int wid = threadIdx.x >> 6, lane = threadIdx.x & 63;
    int node = blockIdx.x * 4 + wid;
    if (node >= N) return;
    int beg = offs[node], cnt = deg[node];
    float ax0 = 0, ay0 = 0, ax1 = 0, ay1 = 0;
    int j = 0;
    for (; j + 8 <= cnt; j += 8) {
        int s0 = csr[beg + j + 0], s1 = csr[beg + j + 1];
        int s2 = csr[beg + j + 2], s3 = csr[beg + j + 3];
        int s4 = csr[beg + j + 4], s5 = csr[beg + j + 5];
        int s6 = csr[beg + j + 6], s7 = csr[beg + j + 7];
        unsigned v0 = inb[(size_t)s0 * 64 + lane];
        unsigned v1 = inb[(size_t)s1 * 64 + lane];
        unsigned v2 = inb[(size_t)s2 * 64 + lane];
        unsigned v3 = inb[(size_t)s3 * 64 + lane];
        unsigned v4 = inb[(size_t)s4 * 64 + lane];
        unsigned v5 = inb[(size_t)s5 * 64 + lane];
        unsigned v6 = inb[(size_t)s6 * 64 + lane];
        unsigned v7 = inb[(size_t)s7 * 64 + lane];
        ax0 += blo(v0) + blo(v2); ay0 += bhi(v0) + bhi(v2);
        ax1 += blo(v1) + blo(v3); ay1 += bhi(v1) + bhi(v3);
        ax0 += blo(v4) + blo(v6); ay0 += bhi(v4) + bhi(v6);
        ax1 += blo(v5) + blo(v7); ay1 += bhi(v5) + bhi(v7);
    }
    for (; j < cnt; ++j) {
        int s = csr[beg + j];
        unsigned v = inb[(size_t)s * 64 + lane];
        ax0 += blo(v); ay0 += bhi(v);
    }
    float id = invd[node];
    float rx = (ax0 + ax1) * id;
    float ry = (ay0 + ay1) * id;
    if (TR) {
        if (cnt > 0) {   // mean(s*v+b) = s*mean(v)+b when deg>0, else 0
            float2 s2 = ((const float2*)sbn)[lane];
            float2 b2 = ((const float2*)bbn)[lane];
            rx = rx * s2.x + b2.x;
            ry = ry * s2.y + b2.y;
        }
    }
    out2[(size_t)node * 64 + lane] = make_float2(rx, ry);
}

// ---------------- fused linear (+bias +L2norm) ----------------
// 32 rows x 128 cols per block (grid 1563 -> ~6 blocks/CU); thread = 4 rows x 4 cols.
// A row-major [32][36] (16B-aligned k-quads); W k-major [32][128]. LDS ~21 KB.
template <int MODE>
__global__ __launch_bounds__(256, 6) void k_lin(
    const float* __restrict__ aggIn,     // [N][128]
    const float* __restrict__ xIn,       // [N][128]
    const float* __restrict__ wt,        // W^T for this layer: [2][128][128] k-major
    const float* __restrict__ bias,      // [128]
    const float* __restrict__ sbn, const float* __restrict__ bbn,   // MODE2
    const float* __restrict__ wfc, const float* __restrict__ bfc,   // MODE2
    float* __restrict__ outp,            // MODE1: h1r [N,128]; MODE2: out [N,8]
    unsigned short* __restrict__ outb,   // MODE1: h1 bf16 [N,128]
    float* __restrict__ bnSum, float* __restrict__ bnSq, int N) {
    __shared__ __align__(16) float As[32 * 36];    // 4.6 KB
    __shared__ __align__(16) float Ws[32 * 128];   // 16 KB

    int tid = threadIdx.x;
    int cg = tid & 31;          // cols cg*4 .. +3
    int rg = tid >> 5;          // rows rg*4 .. +3
    int row0 = blockIdx.x * 32;
    int lane = tid & 63;

    float acc[16];
#pragma unroll
    for (int i = 0; i < 16; i++) acc[i] = 0.f;

    int sr = tid >> 3, sq = tid & 7;     // staging map: row, k-quad

#pragma unroll 1
    for (int chunk = 0; chunk < 8; ++chunk) {
        const float* a = (chunk < 4) ? aggIn : xIn;
        int kb = (chunk & 3) * 32;       // k offset within source row
        // stage A: 32 rows x 8 quads = 256 float4, one per thread
        {
            int arow = row0 + sr;
            f4 v = *(const f4*)&a[(size_t)(arow < N ? arow : 0) * NF + kb + sq * 4];
            if constexpr (MODE == 2) {
                if (chunk >= 4) {        // BN fold on lin_r input features
                    int f = (chunk - 4) * 32 + sq * 4;
                    f4 s = *(const f4*)&sbn[f];
                    f4 b = *(const f4*)&bbn[f];
                    v = v * s + b;
                }
            }
            *(f4*)&As[sr * 36 + sq * 4] = v;
        }
        // stage W: 32 k x 32 quads = 1024 float4
        {
            const f4* wsrc = (const f4*)wt + (chunk >> 2) * 4096 + (chunk & 3) * 1024;
#pragma unroll
            for (int it = 0; it < 4; ++it)
                ((f4*)Ws)[tid + it * 256] = wsrc[tid + it * 256];
        }
        __syncthreads();
#pragma unroll
        for (int kq = 0; kq < 8; ++kq) {
            f4 a0 = *(const f4*)&As[(rg * 4 + 0) * 36 + kq * 4];
            f4 a1 = *(const f4*)&As[(rg * 4 + 1) * 36 + kq * 4];
            f4 a2 = *(const f4*)&As[(rg * 4 + 2) * 36 + kq * 4];
            f4 a3 = *(const f4*)&As[(rg * 4 + 3) * 36 + kq * 4];
#pragma unroll
            for (int t = 0; t < 4; ++t) {
                f4 w = *(const f4*)&Ws[(kq * 4 + t) * 128 + cg * 4];
#pragma unroll
                for (int i = 0; i < 4; ++i) {
                    acc[ 0 + i] += a0[t] * w[i];
                    acc[ 4 + i] += a1[t] * w[i];
                    acc[ 8 + i] += a2[t] * w[i];
                    acc[12 + i] += a3[t] * w[i];
                }
            }
        }
        __syncthreads();
    }

    // bias
    {
        f4 b = *(const f4*)&bias[cg * 4];
#pragma unroll
        for (int j = 0; j < 4; ++j)
#pragma unroll
            for (int i = 0; i < 4; ++i) acc[j * 4 + i] += b[i];
    }
    // row L2 norm: reduce over 32 cg lanes (masks < 32 stay within the cg group)
#pragma unroll
    for (int j = 0; j < 4; ++j) {
        float ss = acc[j * 4] * acc[j * 4] + acc[j * 4 + 1] * acc[j * 4 + 1] +
                   acc[j * 4 + 2] * acc[j * 4 + 2] + acc[j * 4 + 3] * acc[j * 4 + 3];
        ss += __shfl_xor(ss, 1); ss += __shfl_xor(ss, 2); ss += __shfl_xor(ss, 4);
        ss += __shfl_xor(ss, 8); ss += __shfl_xor(ss, 16);
        float inv = 1.0f / fmaxf(sqrtf(ss), 1e-12f);
#pragma unroll
        for (int i = 0; i < 4; ++i) acc[j * 4 + i] *= inv;
    }

    if constexpr (MODE == 1) {
        float* bns = (float*)Ws;         // alias: main loop done
        if (tid < 256) { bns[tid] = 0.f; }
        __syncthreads();
        // relu
#pragma unroll
        for (int i = 0; i < 16; i++) acc[i] = fmaxf(acc[i], 0.f);
        // BN partial sums: per col, over this thread's 4 rows, then rg-pair via xor32
        float su[4], sq4[4];
#pragma unroll
        for (int i = 0; i < 4; i++) { su[i] = 0.f; sq4[i] = 0.f; }
#pragma unroll
        for (int j = 0; j < 4; ++j) {
            bool vj = (row0 + rg * 4 + j) < N;
#pragma unroll
            for (int i = 0; i < 4; i++) {
                float u = vj ? acc[j * 4 + i] : 0.f;
                su[i] += u; sq4[i] += u * u;
            }
        }
#pragma unroll
        for (int i = 0; i < 4; i++) {
            su[i] += __shfl_xor(su[i], 32);
            sq4[i] += __shfl_xor(sq4[i], 32);
        }
        if (lane < 32) {
#pragma unroll
            for (int i = 0; i < 4; i++) {
                atomicAdd(&bns[cg * 4 + i], su[i]);
                atomicAdd(&bns[128 + cg * 4 + i], sq4[i]);
            }
        }
        // store h1r (f32) + h1b (bf16)
#pragma unroll
        for (int j = 0; j < 4; ++j) {
            int row = row0 + rg * 4 + j;
            if (row < N) {
                *(f4*)&outp[(size_t)row * NF + cg * 4] =
                    (f4){acc[j * 4], acc[j * 4 + 1], acc[j * 4 + 2], acc[j * 4 + 3]};
                ushort4 u;
                u.x = f2b(acc[j * 4]);     u.y = f2b(acc[j * 4 + 1]);
                u.z = f2b(acc[j * 4 + 2]); u.w = f2b(acc[j * 4 + 3]);
                *(ushort4*)&outb[(size_t)row * NF + cg * 4] = u;
            }
        }
        __syncthreads();
        if (tid < 128) atomicAdd(&bnSum[tid], bns[tid]);
        else           atomicAdd(&bnSq[tid - 128], bns[tid]);
    } else {
        float* wfcs = (float*)Ws;        // alias: 8 x 128 FC weights
        ((f4*)wfcs)[tid] = ((const f4*)wfc)[tid];   // 1024 floats = 256 f4
        __syncthreads();
#pragma unroll
        for (int j = 0; j < 4; ++j) {
            int row = row0 + rg * 4 + j;
            float o[8];
#pragma unroll
            for (int c = 0; c < 8; c++) {
                f4 w = *(const f4*)&wfcs[c * NF + cg * 4];
                o[c] = acc[j * 4] * w[0] + acc[j * 4 + 1] * w[1] +
                       acc[j * 4 + 2] * w[2] + acc[j * 4 + 3] * w[3];
            }
#pragma unroll
            for (int c = 0; c < 8; c++) {
                o[c] += __shfl_xor(o[c], 1);  o[c] += __shfl_xor(o[c], 2);
                o[c] += __shfl_xor(o[c], 4);  o[c] += __shfl_xor(o[c], 8);
                o[c] += __shfl_xor(o[c], 16);
            }
            if (cg == 0 && row < N) {
#pragma unroll
                for (int c = 0; c < 8; c++) outp[(size_t)row * 8 + c] = o[c] + bfc[c];
            }
        }
    }
}

// ---------------- BN finalize: fold to scale/shift ----------------
__global__ void k_bnfin(const float* __restrict__ bnSum, const float* __restrict__ bnSq,
                        const float* __restrict__ gamma, const float* __restrict__ beta,
                        float* __restrict__ sbn, float* __restrict__ bbn, float n) {
    int f = threadIdx.x;
    float mu = bnSum[f] / n;
    float var = bnSq[f] / n - mu * mu;
    var = fmaxf(var, 0.f);
    float s = gamma[f] / sqrtf(var + 1e-5f);
    sbn[f] = s;
    bbn[f] = beta[f] - mu * s;
}

extern "C" void kernel_launch(void* const* d_in, const int* in_sizes, int n_in,
                              void* d_out, int out_size, void* d_ws, size_t ws_size,
                              hipStream_t stream) {
    const float* x   = (const float*)d_in[0];
    const int*   ei  = (const int*)d_in[1];
    const float* W1l = (const float*)d_in[2];
    const float* b1l = (const float*)d_in[3];
    const float* W1r = (const float*)d_in[4];
    const float* gam = (const float*)d_in[5];
    const float* bet = (const float*)d_in[6];
    const float* W2l = (const float*)d_in[7];
    const float* b2l = (const float*)d_in[8];
    const float* W2r = (const float*)d_in[9];
    const float* Wfc = (const float*)d_in[10];
    const float* bfc = (const float*)d_in[11];
    int N = in_sizes[0] / NF;
    int E = in_sizes[1] / 2;

    char* w = (char*)d_ws;
    size_t o = 0;
    int* deg    = (int*)(w + o); o += (size_t)N * 4;
    int* cursor = (int*)(w + o); o += (size_t)N * 4;
    float* bnSum = (float*)(w + o); o += 512;
    float* bnSq  = (float*)(w + o); o += 512;
    size_t zwords = o / 4;                     // zero region: deg, cursor, bn accum
    int* offs  = (int*)(w + o); o += (size_t)N * 4;
    float* invd = (float*)(w + o); o += (size_t)N * 4;
    int* bsum  = (int*)(w + o); o += 1024;
    int* bbase = (int*)(w + o); o += 1024;
    int* csr   = (int*)(w + o); o += (size_t)E * 4;
    float* wt  = (float*)(w + o); o += (size_t)4 * 128 * 128 * 4;   // W^T x4
    float* sbn = (float*)(w + o); o += 512;
    float* bbn = (float*)(w + o); o += 512;
    float* agg = (float*)(w + o); o += (size_t)N * NF * 4;
    float* h1r = (float*)(w + o); o += (size_t)N * NF * 4;
    unsigned short* xb  = (unsigned short*)(w + o); o += (size_t)N * NF * 2;
    unsigned short* h1b = (unsigned short*)(w + o); o += (size_t)N * NF * 2;
    (void)ws_size; (void)n_in; (void)out_size;

    int NB = (N + 255) / 256;
    int EB = (E + 255) / 256;
    int nodeBlocks = (N + 3) / 4;
    int MB = (N + 31) / 32;
    int CQ = (N * NF / 4 + 255) / 256;

    k_zero<<<(int)((zwords + 255) / 256), 256, 0, stream>>>((int*)d_ws, (int)zwords);
    k_deg<<<EB, 256, 0, stream>>>(ei, E, deg);
    k_cvt<<<CQ, 256, 0, stream>>>((const float4*)x, (ushort4*)xb, N * NF / 4);
    k_prep_w<<<64, 256, 0, stream>>>(W1l, W1r, W2l, W2r, (float4*)wt);
    k_scanA<<<NB, 256, 0, stream>>>(deg, N, bsum);
    k_scanB<<<1, 256, 0, stream>>>(bsum, NB, bbase);
    k_scanC<<<NB, 256, 0, stream>>>(deg, N, bbase, offs, invd);
    k_fill<<<EB, 256, 0, stream>>>(ei, E, offs, cursor, csr);

    // layer 1
    k_agg<false><<<nodeBlocks, 256, 0, stream>>>((const unsigned int*)xb, csr, offs, deg,
                                                 invd, nullptr, nullptr, (float2*)agg, N);
    k_lin<1><<<MB, 256, 0, stream>>>(agg, x, wt, b1l,
                                     nullptr, nullptr, nullptr, nullptr,
                                     h1r, h1b, bnSum, bnSq, N);
    k_bnfin<<<1, 128, 0, stream>>>(bnSum, bnSq, gam, bet, sbn, bbn, (float)N);
    // layer 2 (BN folded into aggregate epilogue / lin_r staging) + fused FC head
    k_agg<true><<<nodeBlocks, 256, 0, stream>>>((const unsigned int*)h1b, csr, offs, deg,
                                                invd, sbn, bbn, (float2*)agg, N);
    k_lin<2><<<MB, 256, 0, stream>>>(agg, h1r, wt + 2 * 16384, b2l,
                                     sbn, bbn, Wfc, bfc,
                                     (float*)d_out, nullptr, nullptr, nullptr, N);
}

// Round 5
// 248.735 us; speedup vs baseline: 1.5510x; 1.2910x over previous
//
#include <hip/hip_runtime.h>
#include <hip/hip_bf16.h>

#define NF 128

typedef float f4 __attribute__((ext_vector_type(4)));
typedef short s16x8 __attribute__((ext_vector_type(8)));
typedef unsigned short u16x8 __attribute__((ext_vector_type(8)));

static __device__ __forceinline__ unsigned short f2b(float f) {
    union { float f; unsigned u; } c; c.f = f;
    unsigned r = c.u + 0x7fffu + ((c.u >> 16) & 1u);
    return (unsigned short)(r >> 16);
}
static __device__ __forceinline__ float blo(unsigned v) { return __uint_as_float(v << 16); }
static __device__ __forceinline__ float bhi(unsigned v) { return __uint_as_float(v & 0xffff0000u); }

// ---------------- zero scratch ----------------
__global__ __launch_bounds__(256) void k_zero(int* __restrict__ p, int nwords) {
    int i = blockIdx.x * 256 + threadIdx.x;
    if (i < nwords) p[i] = 0;
}

// ---------------- x -> bf16 ----------------
__global__ __launch_bounds__(256) void k_cvt(const float4* __restrict__ in,
                                             ushort4* __restrict__ out, int nq) {
    int i = blockIdx.x * 256 + threadIdx.x;
    if (i < nq) {
        float4 v = in[i];
        ushort4 u;
        u.x = f2b(v.x); u.y = f2b(v.y); u.z = f2b(v.z); u.w = f2b(v.w);
        out[i] = u;
    }
}

// ---------------- degree count ----------------
__global__ __launch_bounds__(256) void k_deg(const int* __restrict__ ei, int E,
                                             int* __restrict__ deg) {
    int i = blockIdx.x * 256 + threadIdx.x;
    if (i < E) atomicAdd(&deg[ei[E + i]], 1);
}

// ---------------- 3-kernel deterministic exclusive scan over deg ----------------
__global__ __launch_bounds__(256) void k_scanA(const int* __restrict__ deg, int N,
                                               int* __restrict__ bsum) {
    __shared__ int red[256];
    int tid = threadIdx.x;
    int i = blockIdx.x * 256 + tid;
    int v = (i < N) ? deg[i] : 0;
    red[tid] = v; __syncthreads();
    for (int s = 128; s > 0; s >>= 1) {
        if (tid < s) red[tid] += red[tid + s];
        __syncthreads();
    }
    if (tid == 0) bsum[blockIdx.x] = red[0];
}

__global__ __launch_bounds__(256) void k_scanB(const int* __restrict__ bsum, int NB,
                                               int* __restrict__ bbase) {
    __shared__ int sc[256];
    int tid = threadIdx.x;
    int v = (tid < NB) ? bsum[tid] : 0;
    sc[tid] = v; __syncthreads();
    for (int s = 1; s < 256; s <<= 1) {
        int t = (tid >= s) ? sc[tid - s] : 0;
        __syncthreads();
        sc[tid] += t;
        __syncthreads();
    }
    bbase[tid] = sc[tid] - v;   // exclusive
}

__global__ __launch_bounds__(256) void k_scanC(const int* __restrict__ deg, int N,
                                               const int* __restrict__ bbase,
                                               int* __restrict__ offs,
                                               float* __restrict__ invd) {
    __shared__ int sc[256];
    int tid = threadIdx.x;
    int i = blockIdx.x * 256 + tid;
    int v = (i < N) ? deg[i] : 0;
    sc[tid] = v; __syncthreads();
    for (int s = 1; s < 256; s <<= 1) {
        int t = (tid >= s) ? sc[tid - s] : 0;
        __syncthreads();
        sc[tid] += t;
        __syncthreads();
    }
    if (i < N) {
        offs[i] = bbase[blockIdx.x] + sc[tid] - v;
        invd[i] = (v > 0) ? 1.0f / (float)v : 0.0f;
    }
}

// ---------------- CSR fill ----------------
__global__ __launch_bounds__(256) void k_fill(const int* __restrict__ ei, int E,
                                              const int* __restrict__ offs,
                                              int* __restrict__ cursor,
                                              int* __restrict__ csr) {
    int i = blockIdx.x * 256 + threadIdx.x;
    if (i < E) {
        int d = ei[E + i];
        int p = atomicAdd(&cursor[d], 1);
        csr[offs[d] + p] = ei[i];
    }
}

// ---------------- weight prep -> bf16 MFMA B-layout ----------------
// Per layer: wt[16 ks][128 col][32 k] bf16; entry = W[col][ksg*32+k] (no transpose:
// B-frag[col][k] = W[col][k]). mats: 0=W1l(L0 h0), 1=W1r(L0 h1), 2=W2l(L1 h0).
__global__ __launch_bounds__(256) void k_prep_w(const float* __restrict__ w0,
                                                const float* __restrict__ w1,
                                                const float* __restrict__ w2,
                                                unsigned short* __restrict__ wt) {
    int t = blockIdx.x * 256 + threadIdx.x;     // 0..6143
    if (t >= 6144) return;
    int mat = t >> 11, rem = t & 2047;
    int col = rem >> 4, ks = (rem >> 2) & 3, qq = rem & 3;
    const float* W = (mat == 0) ? w0 : (mat == 1) ? w1 : w2;
    int layer = (mat == 2) ? 1 : 0, half = (mat == 1) ? 1 : 0;
    const float* src = W + col * NF + ks * 32 + qq * 8;
    u16x8 d;
#pragma unroll
    for (int j = 0; j < 8; ++j) d[j] = f2b(src[j]);
    *(u16x8*)(wt + layer * 65536 + (half * 4 + ks) * 4096 + col * 32 + qq * 8) = d;
}

// ---------------- layer-2 lin_r weight: fold BN scale/shift exactly ----------------
// W2r_eff[f][k] = W2r[f][k]*sbn[k];  bias2[f] = b2l[f] + sum_k W2r[f][k]*bbn[k]
__global__ __launch_bounds__(256) void k_prep_w2(const float* __restrict__ w2r,
                                                 const float* __restrict__ sbn,
                                                 const float* __restrict__ b2l,
                                                 const float* __restrict__ bbn,
                                                 unsigned short* __restrict__ wtL2,
                                                 float* __restrict__ bias2) {
    if (blockIdx.x < 8) {
        int t = blockIdx.x * 256 + threadIdx.x;  // 0..2047
        int col = t >> 4, ks = (t >> 2) & 3, qq = t & 3;
        int k0 = ks * 32 + qq * 8;
        u16x8 d;
#pragma unroll
        for (int j = 0; j < 8; ++j) d[j] = f2b(w2r[col * NF + k0 + j] * sbn[k0 + j]);
        *(u16x8*)(wtL2 + (4 + ks) * 4096 + col * 32 + qq * 8) = d;
    } else {
        int f = threadIdx.x;
        if (f < NF) {
            float s = b2l[f];
            for (int k = 0; k < NF; ++k) s += w2r[f * NF + k] * bbn[k];
            bias2[f] = s;
        }
    }
}

// ---------------- aggregate (bf16 gather, f32 accum, bf16 out): one wave per node ----
template <bool TR>
__global__ __launch_bounds__(256) void k_agg(const unsigned int* __restrict__ inb,
                                             const int* __restrict__ csr,
                                             const int* __restrict__ offs,
                                             const int* __restrict__ deg,
                                             const float* __restrict__ invd,
                                             const float* __restrict__ sbn,
                                             const float* __restrict__ bbn,
                                             unsigned int* __restrict__ outB, int N) {
    int wid = threadIdx.x >> 6, lane = threadIdx.x & 63;
    int node = blockIdx.x * 4 + wid;
    if (node >= N) return;
    int beg = offs[node], cnt = deg[node];
    float ax0 = 0, ay0 = 0, ax1 = 0, ay1 = 0;
    int j = 0;
    for (; j + 8 <= cnt; j += 8) {
        int s0 = csr[beg + j + 0], s1 = csr[beg + j + 1];
        int s2 = csr[beg + j + 2], s3 = csr[beg + j + 3];
        int s4 = csr[beg + j + 4], s5 = csr[beg + j + 5];
        int s6 = csr[beg + j + 6], s7 = csr[beg + j + 7];
        unsigned v0 = inb[(size_t)s0 * 64 + lane];
        unsigned v1 = inb[(size_t)s1 * 64 + lane];
        unsigned v2 = inb[(size_t)s2 * 64 + lane];
        unsigned v3 = inb[(size_t)s3 * 64 + lane];
        unsigned v4 = inb[(size_t)s4 * 64 + lane];
        unsigned v5 = inb[(size_t)s5 * 64 + lane];
        unsigned v6 = inb[(size_t)s6 * 64 + lane];
        unsigned v7 = inb[(size_t)s7 * 64 + lane];
        ax0 += blo(v0) + blo(v2); ay0 += bhi(v0) + bhi(v2);
        ax1 += blo(v1) + blo(v3); ay1 += bhi(v1) + bhi(v3);
        ax0 += blo(v4) + blo(v6); ay0 += bhi(v4) + bhi(v6);
        ax1 += blo(v5) + blo(v7); ay1 += bhi(v5) + bhi(v7);
    }
    for (; j < cnt; ++j) {
        int s = csr[beg + j];
        unsigned v = inb[(size_t)s * 64 + lane];
        ax0 += blo(v); ay0 += bhi(v);
    }
    float id = invd[node];
    float rx = (ax0 + ax1) * id;
    float ry = (ay0 + ay1) * id;
    if (TR) {
        if (cnt > 0) {   // mean(s*v+b) = s*mean(v)+b when deg>0, else 0
            float2 s2 = ((const float2*)sbn)[lane];
            float2 b2 = ((const float2*)bbn)[lane];
            rx = rx * s2.x + b2.x;
            ry = ry * s2.y + b2.y;
        }
    }
    outB[(size_t)node * 64 + lane] = (unsigned)f2b(rx) | ((unsigned)f2b(ry) << 16);
}

// ---------------- MFMA linear (+bias +L2norm) ----------------
// 64 rows/block, 4 waves; wave owns 16 rows x 128 cols = 8x mfma_f32_16x16x32_bf16
// tiles over K=256. A-frags & B-frags load straight from global (L2-hot), no LDS
// in the main loop. C layout: col = lane&15, row = (lane>>4)*4 + reg [m89].
template <int MODE>
__global__ __launch_bounds__(256) void k_lin(
    const unsigned short* __restrict__ aggB,   // [N][128] bf16
    const unsigned short* __restrict__ src2,   // [N][128] bf16 (xb / h1b)
    const unsigned short* __restrict__ wt,     // layer base: [16][128][32] bf16
    const float* __restrict__ bias,            // [128] (layer2: BN-folded)
    const float* __restrict__ wfc, const float* __restrict__ bfc,   // MODE2
    unsigned short* __restrict__ outb,         // MODE1: h1b bf16 [N,128]
    float* __restrict__ outf,                  // MODE2: out [N,8]
    float* __restrict__ bnSum, float* __restrict__ bnSq, int N) {
    __shared__ float sbuf[1024];               // MODE1: bn partials; MODE2: wfc

    int tid = threadIdx.x;
    int lane = tid & 63;
    int q = lane >> 4, m = lane & 15;
    int row_base = blockIdx.x * 64 + (tid >> 6) * 16;

    if constexpr (MODE == 1) {
        if (tid < 256) { sbuf[tid] = 0.f; }
    } else {
        *(f4*)&sbuf[tid * 4] = ((const f4*)wfc)[tid];   // 1024 floats
    }
    __syncthreads();

    int r = row_base + m; if (r >= N) r = N - 1;       // clamp (outputs guarded)
    const unsigned short* a1 = aggB + (size_t)r * NF;
    const unsigned short* a2 = src2 + (size_t)r * NF;

    s16x8 afr[8];
#pragma unroll
    for (int ks = 0; ks < 4; ++ks) afr[ks] = *(const s16x8*)(a1 + ks * 32 + q * 8);
#pragma unroll
    for (int ks = 0; ks < 4; ++ks) afr[4 + ks] = *(const s16x8*)(a2 + ks * 32 + q * 8);

    f4 acc[8];
#pragma unroll
    for (int c = 0; c < 8; ++c) acc[c] = (f4){0.f, 0.f, 0.f, 0.f};

    const unsigned short* wb = wt + m * 32 + q * 8;
#pragma unroll
    for (int ks = 0; ks < 8; ++ks) {
#pragma unroll
        for (int c = 0; c < 8; ++c) {
            s16x8 bfr = *(const s16x8*)(wb + ks * 4096 + c * 512);
            acc[c] = __builtin_amdgcn_mfma_f32_16x16x32_bf16(afr[ks], bfr, acc[c], 0, 0, 0);
        }
    }

    // bias (col = c*16+m)
#pragma unroll
    for (int c = 0; c < 8; ++c) {
        float b = bias[c * 16 + m];
#pragma unroll
        for (int i = 0; i < 4; ++i) acc[c][i] += b;
    }
    // row L2 norm: row = row_base + q*4 + i lives in the 16 lanes of this q-group
    float ss[4];
#pragma unroll
    for (int i = 0; i < 4; ++i) {
        float s = 0.f;
#pragma unroll
        for (int c = 0; c < 8; ++c) s += acc[c][i] * acc[c][i];
        s += __shfl_xor(s, 1); s += __shfl_xor(s, 2);
        s += __shfl_xor(s, 4); s += __shfl_xor(s, 8);
        ss[i] = 1.0f / fmaxf(sqrtf(s), 1e-12f);
    }
#pragma unroll
    for (int c = 0; c < 8; ++c)
#pragma unroll
        for (int i = 0; i < 4; ++i) acc[c][i] *= ss[i];

    if constexpr (MODE == 1) {
        // relu
#pragma unroll
        for (int c = 0; c < 8; ++c)
#pragma unroll
            for (int i = 0; i < 4; ++i) acc[c][i] = fmaxf(acc[c][i], 0.f);
        // store h1 bf16
#pragma unroll
        for (int i = 0; i < 4; ++i) {
            int row = row_base + q * 4 + i;
            if (row < N) {
#pragma unroll
                for (int c = 0; c < 8; ++c)
                    outb[(size_t)row * NF + c * 16 + m] = f2b(acc[c][i]);
            }
        }
        // BN partial sums per col over this wave's 16 rows
        float su[8], sq[8];
#pragma unroll
        for (int c = 0; c < 8; ++c) { su[c] = 0.f; sq[c] = 0.f; }
#pragma unroll
        for (int i = 0; i < 4; ++i) {
            bool vi = (row_base + q * 4 + i) < N;
#pragma unroll
            for (int c = 0; c < 8; ++c) {
                float u = vi ? acc[c][i] : 0.f;
                su[c] += u; sq[c] += u * u;
            }
        }
#pragma unroll
        for (int c = 0; c < 8; ++c) {
            su[c] += __shfl_xor(su[c], 16); su[c] += __shfl_xor(su[c], 32);
            sq[c] += __shfl_xor(sq[c], 16); sq[c] += __shfl_xor(sq[c], 32);
        }
        if (lane < 16) {
#pragma unroll
            for (int c = 0; c < 8; ++c) {
                atomicAdd(&sbuf[c * 16 + m], su[c]);
                atomicAdd(&sbuf[128 + c * 16 + m], sq[c]);
            }
        }
        __syncthreads();
        if (tid < 128)      atomicAdd(&bnSum[tid], sbuf[tid]);
        else if (tid < 256) atomicAdd(&bnSq[tid - 128], sbuf[tid]);
    } else {
        // fused FC head: out[row][cls] = sum_col h2[row][col]*wfc[cls][col] + bfc
        float o[8][4];
#pragma unroll
        for (int cls = 0; cls < 8; ++cls)
#pragma unroll
            for (int i = 0; i < 4; ++i) o[cls][i] = 0.f;
#pragma unroll
        for (int cls = 0; cls < 8; ++cls) {
#pragma unroll
            for (int c = 0; c < 8; ++c) {
                float wv = sbuf[cls * NF + c * 16 + m];
#pragma unroll
                for (int i = 0; i < 4; ++i) o[cls][i] += acc[c][i] * wv;
            }
#pragma unroll
            for (int i = 0; i < 4; ++i) {
                float t = o[cls][i];
                t += __shfl_xor(t, 1); t += __shfl_xor(t, 2);
                t += __shfl_xor(t, 4); t += __shfl_xor(t, 8);
                o[cls][i] = t;
            }
        }
        float sel[4] = {0.f, 0.f, 0.f, 0.f};
#pragma unroll
        for (int cls = 0; cls < 8; ++cls) {
            bool p = (m == cls);
#pragma unroll
            for (int i = 0; i < 4; ++i) sel[i] = p ? o[cls][i] : sel[i];
        }
        if (m < 8) {
            float bb = bfc[m];
#pragma unroll
            for (int i = 0; i < 4; ++i) {
                int row = row_base + q * 4 + i;
                if (row < N) outf[(size_t)row * 8 + m] = sel[i] + bb;
            }
        }
    }
}

// ---------------- BN finalize: fold to scale/shift ----------------
__global__ void k_bnfin(const float* __restrict__ bnSum, const float* __restrict__ bnSq,
                        const float* __restrict__ gamma, const float* __restrict__ beta,
                        float* __restrict__ sbn, float* __restrict__ bbn, float n) {
    int f = threadIdx.x;
    float mu = bnSum[f] / n;
    float var = bnSq[f] / n - mu * mu;
    var = fmaxf(var, 0.f);
    float s = gamma[f] / sqrtf(var + 1e-5f);
    sbn[f] = s;
    bbn[f] = beta[f] - mu * s;
}

extern "C" void kernel_launch(void* const* d_in, const int* in_sizes, int n_in,
                              void* d_out, int out_size, void* d_ws, size_t ws_size,
                              hipStream_t stream) {
    const float* x   = (const float*)d_in[0];
    const int*   ei  = (const int*)d_in[1];
    const float* W1l = (const float*)d_in[2];
    const float* b1l = (const float*)d_in[3];
    const float* W1r = (const float*)d_in[4];
    const float* gam = (const float*)d_in[5];
    const float* bet = (const float*)d_in[6];
    const float* W2l = (const float*)d_in[7];
    const float* b2l = (const float*)d_in[8];
    const float* W2r = (const float*)d_in[9];
    const float* Wfc = (const float*)d_in[10];
    const float* bfc = (const float*)d_in[11];
    int N = in_sizes[0] / NF;
    int E = in_sizes[1] / 2;

    char* w = (char*)d_ws;
    size_t o = 0;
    int* deg    = (int*)(w + o); o += (size_t)N * 4;
    int* cursor = (int*)(w + o); o += (size_t)N * 4;
    float* bnSum = (float*)(w + o); o += 512;
    float* bnSq  = (float*)(w + o); o += 512;
    size_t zwords = o / 4;                     // zero region: deg, cursor, bn accum
    int* offs  = (int*)(w + o); o += (size_t)N * 4;
    float* invd = (float*)(w + o); o += (size_t)N * 4;
    int* bsum  = (int*)(w + o); o += 1024;
    int* bbase = (int*)(w + o); o += 1024;
    int* csr   = (int*)(w + o); o += (size_t)E * 4;
    unsigned short* wt = (unsigned short*)(w + o); o += (size_t)2 * 65536 * 2;  // bf16 B-layout
    float* sbn   = (float*)(w + o); o += 512;
    float* bbn   = (float*)(w + o); o += 512;
    float* bias2 = (float*)(w + o); o += 512;
    unsigned short* xb   = (unsigned short*)(w + o); o += (size_t)N * NF * 2;
    unsigned short* aggB = (unsigned short*)(w + o); o += (size_t)N * NF * 2;
    unsigned short* h1b  = (unsigned short*)(w + o); o += (size_t)N * NF * 2;
    (void)ws_size; (void)n_in; (void)out_size;

    int NB = (N + 255) / 256;
    int EB = (E + 255) / 256;
    int nodeBlocks = (N + 3) / 4;
    int LB = (N + 63) / 64;
    int CQ = (N * NF / 4 + 255) / 256;

    k_zero<<<(int)((zwords + 255) / 256), 256, 0, stream>>>((int*)d_ws, (int)zwords);
    k_deg<<<EB, 256, 0, stream>>>(ei, E, deg);
    k_cvt<<<CQ, 256, 0, stream>>>((const float4*)x, (ushort4*)xb, N * NF / 4);
    k_prep_w<<<24, 256, 0, stream>>>(W1l, W1r, W2l, wt);
    k_scanA<<<NB, 256, 0, stream>>>(deg, N, bsum);
    k_scanB<<<1, 256, 0, stream>>>(bsum, NB, bbase);
    k_scanC<<<NB, 256, 0, stream>>>(deg, N, bbase, offs, invd);
    k_fill<<<EB, 256, 0, stream>>>(ei, E, offs, cursor, csr);

    // layer 1
    k_agg<false><<<nodeBlocks, 256, 0, stream>>>((const unsigned int*)xb, csr, offs, deg,
                                                 invd, nullptr, nullptr,
                                                 (unsigned int*)aggB, N);
    k_lin<1><<<LB, 256, 0, stream>>>(aggB, xb, wt, b1l, nullptr, nullptr,
                                     h1b, nullptr, bnSum, bnSq, N);
    k_bnfin<<<1, 128, 0, stream>>>(bnSum, bnSq, gam, bet, sbn, bbn, (float)N);
    k_prep_w2<<<9, 256, 0, stream>>>(W2r, sbn, b2l, bbn, wt + 65536, bias2);
    // layer 2 (BN folded: agg epilogue for lin_l, weights for lin_r) + fused FC head
    k_agg<true><<<nodeBlocks, 256, 0, stream>>>((const unsigned int*)h1b, csr, offs, deg,
                                                invd, sbn, bbn, (unsigned int*)aggB, N);
    k_lin<2><<<LB, 256, 0, stream>>>(aggB, h1b, wt + 65536, bias2, Wfc, bfc,
                                     nullptr, (float*)d_out, nullptr, nullptr, N);
}

// Round 6
// 243.109 us; speedup vs baseline: 1.5869x; 1.0231x over previous
//
#include <hip/hip_runtime.h>
#include <hip/hip_bf16.h>

#define NF 128

typedef float f4 __attribute__((ext_vector_type(4)));
typedef short s16x8 __attribute__((ext_vector_type(8)));
typedef unsigned short u16x8 __attribute__((ext_vector_type(8)));

static __device__ __forceinline__ unsigned short f2b(float f) {
    union { float f; unsigned u; } c; c.f = f;
    unsigned r = c.u + 0x7fffu + ((c.u >> 16) & 1u);
    return (unsigned short)(r >> 16);
}
static __device__ __forceinline__ float blo(unsigned v) { return __uint_as_float(v << 16); }
static __device__ __forceinline__ float bhi(unsigned v) { return __uint_as_float(v & 0xffff0000u); }

// ---------------- zero scratch ----------------
__global__ __launch_bounds__(256) void k_zero(int* __restrict__ p, int nwords) {
    int i = blockIdx.x * 256 + threadIdx.x;
    if (i < nwords) p[i] = 0;
}

// ---------------- x -> bf16, XCD-sliced layout [4][N][32 feats] (u32 = 2 feats) ----
__global__ __launch_bounds__(256) void k_cvt(const float* __restrict__ x,
                                             unsigned* __restrict__ out32, int N) {
    int i = blockIdx.x * 256 + threadIdx.x;
    if (i >= N * 64) return;
    int n = i >> 6, l = i & 63;          // l = feature-pair 0..63
    int s = l >> 4, li = l & 15;         // slice, pair-within-slice
    float2 v = *(const float2*)(x + (size_t)n * NF + l * 2);
    out32[(size_t)s * N * 16 + (size_t)n * 16 + li] =
        (unsigned)f2b(v.x) | ((unsigned)f2b(v.y) << 16);
}

// ---------------- degree count ----------------
__global__ __launch_bounds__(256) void k_deg(const int* __restrict__ ei, int E,
                                             int* __restrict__ deg) {
    int i = blockIdx.x * 256 + threadIdx.x;
    if (i < E) atomicAdd(&deg[ei[E + i]], 1);
}

// ---------------- 3-kernel deterministic exclusive scan over deg ----------------
__global__ __launch_bounds__(256) void k_scanA(const int* __restrict__ deg, int N,
                                               int* __restrict__ bsum) {
    __shared__ int red[256];
    int tid = threadIdx.x;
    int i = blockIdx.x * 256 + tid;
    int v = (i < N) ? deg[i] : 0;
    red[tid] = v; __syncthreads();
    for (int s = 128; s > 0; s >>= 1) {
        if (tid < s) red[tid] += red[tid + s];
        __syncthreads();
    }
    if (tid == 0) bsum[blockIdx.x] = red[0];
}

__global__ __launch_bounds__(256) void k_scanB(const int* __restrict__ bsum, int NB,
                                               int* __restrict__ bbase) {
    __shared__ int sc[256];
    int tid = threadIdx.x;
    int v = (tid < NB) ? bsum[tid] : 0;
    sc[tid] = v; __syncthreads();
    for (int s = 1; s < 256; s <<= 1) {
        int t = (tid >= s) ? sc[tid - s] : 0;
        __syncthreads();
        sc[tid] += t;
        __syncthreads();
    }
    bbase[tid] = sc[tid] - v;   // exclusive
}

__global__ __launch_bounds__(256) void k_scanC(const int* __restrict__ deg, int N,
                                               const int* __restrict__ bbase,
                                               int* __restrict__ offs) {
    __shared__ int sc[256];
    int tid = threadIdx.x;
    int i = blockIdx.x * 256 + tid;
    int v = (i < N) ? deg[i] : 0;
    sc[tid] = v; __syncthreads();
    for (int s = 1; s < 256; s <<= 1) {
        int t = (tid >= s) ? sc[tid - s] : 0;
        __syncthreads();
        sc[tid] += t;
        __syncthreads();
    }
    if (i < N) {
        offs[i] = bbase[blockIdx.x] + sc[tid] - v;
        if (i == N - 1) offs[N] = bbase[blockIdx.x] + sc[tid];   // sentinel = E
    }
}

// ---------------- CSR fill (u16 src; requires N <= 65536) ----------------
__global__ __launch_bounds__(256) void k_fill(const int* __restrict__ ei, int E,
                                              const int* __restrict__ offs,
                                              int* __restrict__ cursor,
                                              unsigned short* __restrict__ csr) {
    int i = blockIdx.x * 256 + threadIdx.x;
    if (i < E) {
        int d = ei[E + i];
        int p = atomicAdd(&cursor[d], 1);
        csr[offs[d] + p] = (unsigned short)ei[i];
    }
}

// ---------------- weight prep -> bf16 MFMA B-layout ----------------
// Per layer: wt[8 ks][128 col][32 k] bf16; entry = W[col][ks*32+k].
// mats: 0=W1l(L0 half0), 1=W1r(L0 half1), 2=W2l(L1 half0).
__global__ __launch_bounds__(256) void k_prep_w(const float* __restrict__ w0,
                                                const float* __restrict__ w1,
                                                const float* __restrict__ w2,
                                                unsigned short* __restrict__ wt) {
    int t = blockIdx.x * 256 + threadIdx.x;     // 0..6143
    if (t >= 6144) return;
    int mat = t >> 11, rem = t & 2047;
    int col = rem >> 4, ks = (rem >> 2) & 3, qq = rem & 3;
    const float* W = (mat == 0) ? w0 : (mat == 1) ? w1 : w2;
    int layer = (mat == 2) ? 1 : 0, half = (mat == 1) ? 1 : 0;
    const float* src = W + col * NF + ks * 32 + qq * 8;
    u16x8 d;
#pragma unroll
    for (int j = 0; j < 8; ++j) d[j] = f2b(src[j]);
    *(u16x8*)(wt + layer * 65536 + (half * 4 + ks) * 4096 + col * 32 + qq * 8) = d;
}

// ---------------- layer-2 lin_r weight: fold BN scale/shift exactly ----------------
__global__ __launch_bounds__(256) void k_prep_w2(const float* __restrict__ w2r,
                                                 const float* __restrict__ sbn,
                                                 const float* __restrict__ b2l,
                                                 const float* __restrict__ bbn,
                                                 unsigned short* __restrict__ wtL2,
                                                 float* __restrict__ bias2) {
    if (blockIdx.x < 8) {
        int t = blockIdx.x * 256 + threadIdx.x;  // 0..2047
        int col = t >> 4, ks = (t >> 2) & 3, qq = t & 3;
        int k0 = ks * 32 + qq * 8;
        u16x8 d;
#pragma unroll
        for (int j = 0; j < 8; ++j) d[j] = f2b(w2r[col * NF + k0 + j] * sbn[k0 + j]);
        *(u16x8*)(wtL2 + (4 + ks) * 4096 + col * 32 + qq * 8) = d;
    } else {
        int f = threadIdx.x;
        if (f < NF) {
            float s = b2l[f];
            for (int k = 0; k < NF; ++k) s += w2r[f * NF + k] * bbn[k];
            bias2[f] = s;
        }
    }
}

// ---------------- aggregate, XCD-sliced ----------------
// slice s = (blockIdx%8)>>1 -> pinned to one XCD pair (round-robin dispatch);
// slice table [N][32 feats] = 3.2 MB bf16, L2-resident per XCD.
// 16-lane group per node; 16 nodes per block per slice.
template <bool TR>
__global__ __launch_bounds__(256) void k_agg(const unsigned* __restrict__ tab,  // [4][N][16] u32
                                             const unsigned short* __restrict__ csr,
                                             const int* __restrict__ offs,
                                             const float* __restrict__ sbn,
                                             const float* __restrict__ bbn,
                                             unsigned* __restrict__ outT, int N) {
    int b = blockIdx.x;
    int s = (b & 7) >> 1;
    int chunk = (b >> 3) * 2 + (b & 1);
    int tid = threadIdx.x;
    int wid = tid >> 6, lane = tid & 63, g = lane >> 4, li = lane & 15;
    int node = chunk * 16 + wid * 4 + g;
    if (node >= N) return;
    int beg = offs[node], cnt = offs[node + 1] - beg;
    const unsigned* T = tab + (size_t)s * N * 16;
    float ax0 = 0, ay0 = 0, ax1 = 0, ay1 = 0;
    int j = 0;
    for (; j + 4 <= cnt; j += 4) {
        int s0 = csr[beg + j + 0], s1 = csr[beg + j + 1];
        int s2 = csr[beg + j + 2], s3 = csr[beg + j + 3];
        unsigned v0 = T[(size_t)s0 * 16 + li];
        unsigned v1 = T[(size_t)s1 * 16 + li];
        unsigned v2 = T[(size_t)s2 * 16 + li];
        unsigned v3 = T[(size_t)s3 * 16 + li];
        ax0 += blo(v0) + blo(v2); ay0 += bhi(v0) + bhi(v2);
        ax1 += blo(v1) + blo(v3); ay1 += bhi(v1) + bhi(v3);
    }
    for (; j < cnt; ++j) {
        unsigned v = T[(size_t)csr[beg + j] * 16 + li];
        ax0 += blo(v); ay0 += bhi(v);
    }
    float id = (cnt > 0) ? 1.0f / (float)cnt : 0.f;
    float rx = (ax0 + ax1) * id;
    float ry = (ay0 + ay1) * id;
    if (TR) {
        if (cnt > 0) {   // mean(s*v+b) = s*mean(v)+b when deg>0, else 0
            float2 sc = ((const float2*)sbn)[s * 16 + li];
            float2 bc = ((const float2*)bbn)[s * 16 + li];
            rx = rx * sc.x + bc.x;
            ry = ry * sc.y + bc.y;
        }
    }
    outT[(size_t)s * N * 16 + (size_t)node * 16 + li] =
        (unsigned)f2b(rx) | ((unsigned)f2b(ry) << 16);
}

// ---------------- MFMA linear (+bias +L2norm) ----------------
// 64 rows/block, 4 waves; wave = 16 rows x 128 cols = 8x mfma_f32_16x16x32_bf16
// over K=256. Inputs in sliced layout: feat ks*32+q*8 lives in slice ks.
// C layout: col = lane&15, row = (lane>>4)*4 + reg [m89].
template <int MODE>
__global__ __launch_bounds__(256) void k_lin(
    const unsigned short* __restrict__ aggB,   // sliced [4][N][32] bf16
    const unsigned short* __restrict__ src2,   // sliced [4][N][32] bf16 (xb / h1b)
    const unsigned short* __restrict__ wt,     // layer base: [8][128][32] bf16
    const float* __restrict__ bias,            // [128] (layer2: BN-folded)
    const float* __restrict__ wfc, const float* __restrict__ bfc,   // MODE2
    unsigned short* __restrict__ outb,         // MODE1: h1b sliced [4][N][32]
    float* __restrict__ outf,                  // MODE2: out [N,8]
    float* __restrict__ bnSum, float* __restrict__ bnSq, int N) {
    __shared__ float sbuf[1024];               // MODE1: bn partials; MODE2: wfc

    int tid = threadIdx.x;
    int lane = tid & 63;
    int q = lane >> 4, m = lane & 15;
    int row_base = blockIdx.x * 64 + (tid >> 6) * 16;

    if constexpr (MODE == 1) {
        if (tid < 256) { sbuf[tid] = 0.f; }
    } else {
        *(f4*)&sbuf[tid * 4] = ((const f4*)wfc)[tid];   // 1024 floats
    }
    __syncthreads();

    int r = row_base + m; if (r >= N) r = N - 1;       // clamp (outputs guarded)
    size_t rr = (size_t)r * 32 + q * 8;

    s16x8 afr[8];
#pragma unroll
    for (int ks = 0; ks < 4; ++ks) afr[ks] = *(const s16x8*)(aggB + (size_t)ks * N * 32 + rr);
#pragma unroll
    for (int ks = 0; ks < 4; ++ks) afr[4 + ks] = *(const s16x8*)(src2 + (size_t)ks * N * 32 + rr);

    f4 acc[8];
#pragma unroll
    for (int c = 0; c < 8; ++c) acc[c] = (f4){0.f, 0.f, 0.f, 0.f};

    const unsigned short* wb = wt + m * 32 + q * 8;
#pragma unroll
    for (int ks = 0; ks < 8; ++ks) {
#pragma unroll
        for (int c = 0; c < 8; ++c) {
            s16x8 bfr = *(const s16x8*)(wb + ks * 4096 + c * 512);
            acc[c] = __builtin_amdgcn_mfma_f32_16x16x32_bf16(afr[ks], bfr, acc[c], 0, 0, 0);
        }
    }

    // bias (col = c*16+m)
#pragma unroll
    for (int c = 0; c < 8; ++c) {
        float b = bias[c * 16 + m];
#pragma unroll
        for (int i = 0; i < 4; ++i) acc[c][i] += b;
    }
    // row L2 norm: row = row_base + q*4 + i lives in the 16 lanes of this q-group
    float ss[4];
#pragma unroll
    for (int i = 0; i < 4; ++i) {
        float s = 0.f;
#pragma unroll
        for (int c = 0; c < 8; ++c) s += acc[c][i] * acc[c][i];
        s += __shfl_xor(s, 1); s += __shfl_xor(s, 2);
        s += __shfl_xor(s, 4); s += __shfl_xor(s, 8);
        ss[i] = 1.0f / fmaxf(sqrtf(s), 1e-12f);
    }
#pragma unroll
    for (int c = 0; c < 8; ++c)
#pragma unroll
        for (int i = 0; i < 4; ++i) acc[c][i] *= ss[i];

    if constexpr (MODE == 1) {
        // relu
#pragma unroll
        for (int c = 0; c < 8; ++c)
#pragma unroll
            for (int i = 0; i < 4; ++i) acc[c][i] = fmaxf(acc[c][i], 0.f);
        // store h1 bf16, sliced: feat c*16+m -> slice c>>1, offset (c&1)*16+m
#pragma unroll
        for (int i = 0; i < 4; ++i) {
            int row = row_base + q * 4 + i;
            if (row < N) {
#pragma unroll
                for (int c = 0; c < 8; ++c)
                    outb[(size_t)(c >> 1) * N * 32 + (size_t)row * 32 + (c & 1) * 16 + m] =
                        f2b(acc[c][i]);
            }
        }
        // BN partial sums per col over this wave's 16 rows
        float su[8], sq[8];
#pragma unroll
        for (int c = 0; c < 8; ++c) { su[c] = 0.f; sq[c] = 0.f; }
#pragma unroll
        for (int i = 0; i < 4; ++i) {
            bool vi = (row_base + q * 4 + i) < N;
#pragma unroll
            for (int c = 0; c < 8; ++c) {
                float u = vi ? acc[c][i] : 0.f;
                su[c] += u; sq[c] += u * u;
            }
        }
#pragma unroll
        for (int c = 0; c < 8; ++c) {
            su[c] += __shfl_xor(su[c], 16); su[c] += __shfl_xor(su[c], 32);
            sq[c] += __shfl_xor(sq[c], 16); sq[c] += __shfl_xor(sq[c], 32);
        }
        if (lane < 16) {
#pragma unroll
            for (int c = 0; c < 8; ++c) {
                atomicAdd(&sbuf[c * 16 + m], su[c]);
                atomicAdd(&sbuf[128 + c * 16 + m], sq[c]);
            }
        }
        __syncthreads();
        if (tid < 128)      atomicAdd(&bnSum[tid], sbuf[tid]);
        else if (tid < 256) atomicAdd(&bnSq[tid - 128], sbuf[tid]);
    } else {
        // fused FC head: out[row][cls] = sum_col h2[row][col]*wfc[cls][col] + bfc
        float o[8][4];
#pragma unroll
        for (int cls = 0; cls < 8; ++cls)
#pragma unroll
            for (int i = 0; i < 4; ++i) o[cls][i] = 0.f;
#pragma unroll
        for (int cls = 0; cls < 8; ++cls) {
#pragma unroll
            for (int c = 0; c < 8; ++c) {
                float wv = sbuf[cls * NF + c * 16 + m];
#pragma unroll
                for (int i = 0; i < 4; ++i) o[cls][i] += acc[c][i] * wv;
            }
#pragma unroll
            for (int i = 0; i < 4; ++i) {
                float t = o[cls][i];
                t += __shfl_xor(t, 1); t += __shfl_xor(t, 2);
                t += __shfl_xor(t, 4); t += __shfl_xor(t, 8);
                o[cls][i] = t;
            }
        }
        float sel[4] = {0.f, 0.f, 0.f, 0.f};
#pragma unroll
        for (int cls = 0; cls < 8; ++cls) {
            bool p = (m == cls);
#pragma unroll
            for (int i = 0; i < 4; ++i) sel[i] = p ? o[cls][i] : sel[i];
        }
        if (m < 8) {
            float bb = bfc[m];
#pragma unroll
            for (int i = 0; i < 4; ++i) {
                int row = row_base + q * 4 + i;
                if (row < N) outf[(size_t)row * 8 + m] = sel[i] + bb;
            }
        }
    }
}

// ---------------- BN finalize: fold to scale/shift ----------------
__global__ void k_bnfin(const float* __restrict__ bnSum, const float* __restrict__ bnSq,
                        const float* __restrict__ gamma, const float* __restrict__ beta,
                        float* __restrict__ sbn, float* __restrict__ bbn, float n) {
    int f = threadIdx.x;
    float mu = bnSum[f] / n;
    float var = bnSq[f] / n - mu * mu;
    var = fmaxf(var, 0.f);
    float s = gamma[f] / sqrtf(var + 1e-5f);
    sbn[f] = s;
    bbn[f] = beta[f] - mu * s;
}

extern "C" void kernel_launch(void* const* d_in, const int* in_sizes, int n_in,
                              void* d_out, int out_size, void* d_ws, size_t ws_size,
                              hipStream_t stream) {
    const float* x   = (const float*)d_in[0];
    const int*   ei  = (const int*)d_in[1];
    const float* W1l = (const float*)d_in[2];
    const float* b1l = (const float*)d_in[3];
    const float* W1r = (const float*)d_in[4];
    const float* gam = (const float*)d_in[5];
    const float* bet = (const float*)d_in[6];
    const float* W2l = (const float*)d_in[7];
    const float* b2l = (const float*)d_in[8];
    const float* W2r = (const float*)d_in[9];
    const float* Wfc = (const float*)d_in[10];
    const float* bfc = (const float*)d_in[11];
    int N = in_sizes[0] / NF;
    int E = in_sizes[1] / 2;

    char* w = (char*)d_ws;
    size_t o = 0;
#define ALO(nbytes) (o = (o + 255) & ~(size_t)255, o += (nbytes), (w + o - (nbytes)))
    int* deg    = (int*)ALO((size_t)N * 4);
    int* cursor = (int*)ALO((size_t)N * 4);
    float* bnSum = (float*)ALO(512);
    float* bnSq  = (float*)ALO(512);
    size_t zwords = o / 4;                     // zero region: deg, cursor, bn accum
    int* offs  = (int*)ALO((size_t)(N + 1) * 4);
    int* bsum  = (int*)ALO(1024);
    int* bbase = (int*)ALO(1024);
    unsigned short* csr = (unsigned short*)ALO((size_t)E * 2);
    unsigned short* wt  = (unsigned short*)ALO((size_t)2 * 65536 * 2);
    float* sbn   = (float*)ALO(512);
    float* bbn   = (float*)ALO(512);
    float* bias2 = (float*)ALO(512);
    unsigned short* xb   = (unsigned short*)ALO((size_t)N * NF * 2);  // sliced [4][N][32]
    unsigned short* aggB = (unsigned short*)ALO((size_t)N * NF * 2);  // sliced
    unsigned short* h1b  = (unsigned short*)ALO((size_t)N * NF * 2);  // sliced
#undef ALO
    (void)ws_size; (void)n_in; (void)out_size;

    int NB = (N + 255) / 256;
    int EB = (E + 255) / 256;
    int aggBlocks = ((N + 31) / 32) * 8;       // (chunk-pairs) x 8 for XCD slice pinning
    int LB = (N + 63) / 64;
    int CV = (N * 64 + 255) / 256;

    k_zero<<<(int)((zwords + 255) / 256), 256, 0, stream>>>((int*)d_ws, (int)zwords);
    k_deg<<<EB, 256, 0, stream>>>(ei, E, deg);
    k_cvt<<<CV, 256, 0, stream>>>(x, (unsigned*)xb, N);
    k_prep_w<<<24, 256, 0, stream>>>(W1l, W1r, W2l, wt);
    k_scanA<<<NB, 256, 0, stream>>>(deg, N, bsum);
    k_scanB<<<1, 256, 0, stream>>>(bsum, NB, bbase);
    k_scanC<<<NB, 256, 0, stream>>>(deg, N, bbase, offs);
    k_fill<<<EB, 256, 0, stream>>>(ei, E, offs, cursor, csr);

    // layer 1
    k_agg<false><<<aggBlocks, 256, 0, stream>>>((const unsigned*)xb, csr, offs,
                                                nullptr, nullptr, (unsigned*)aggB, N);
    k_lin<1><<<LB, 256, 0, stream>>>(aggB, xb, wt, b1l, nullptr, nullptr,
                                     h1b, nullptr, bnSum, bnSq, N);
    k_bnfin<<<1, 128, 0, stream>>>(bnSum, bnSq, gam, bet, sbn, bbn, (float)N);
    k_prep_w2<<<9, 256, 0, stream>>>(W2r, sbn, b2l, bbn, wt + 65536, bias2);
    // layer 2 (BN folded: agg epilogue for lin_l, weights for lin_r) + fused FC head
    k_agg<true><<<aggBlocks, 256, 0, stream>>>((const unsigned*)h1b, csr, offs,
                                               sbn, bbn, (unsigned*)aggB, N);
    k_lin<2><<<LB, 256, 0, stream>>>(aggB, h1b, wt + 65536, bias2, Wfc, bfc,
                                     nullptr, (float*)d_out, nullptr, nullptr, N);
}

// Round 7
// 215.927 us; speedup vs baseline: 1.7867x; 1.1259x over previous
//
#include <hip/hip_runtime.h>
#include <hip/hip_bf16.h>

#define NF 128

typedef float f4 __attribute__((ext_vector_type(4)));
typedef short s16x8 __attribute__((ext_vector_type(8)));
typedef unsigned short u16x8 __attribute__((ext_vector_type(8)));

static __device__ __forceinline__ unsigned short f2b(float f) {
    union { float f; unsigned u; } c; c.f = f;
    unsigned r = c.u + 0x7fffu + ((c.u >> 16) & 1u);
    return (unsigned short)(r >> 16);
}
static __device__ __forceinline__ float blo(unsigned v) { return __uint_as_float(v << 16); }
static __device__ __forceinline__ float bhi(unsigned v) { return __uint_as_float(v & 0xffff0000u); }

// ---------------- zero scratch ----------------
__global__ __launch_bounds__(256) void k_zero(int* __restrict__ p, int nwords) {
    int i = blockIdx.x * 256 + threadIdx.x;
    if (i < nwords) p[i] = 0;
}

// ---------------- x -> bf16, XCD-sliced layout [4][N][32 feats] (u32 = 2 feats) ----
__global__ __launch_bounds__(256) void k_cvt(const float* __restrict__ x,
                                             unsigned* __restrict__ out32, int N) {
    int i = blockIdx.x * 256 + threadIdx.x;
    if (i >= N * 64) return;
    int n = i >> 6, l = i & 63;          // l = feature-pair 0..63
    int s = l >> 4, li = l & 15;         // slice, pair-within-slice
    float2 v = *(const float2*)(x + (size_t)n * NF + l * 2);
    out32[(size_t)s * N * 16 + (size_t)n * 16 + li] =
        (unsigned)f2b(v.x) | ((unsigned)f2b(v.y) << 16);
}

// ---------------- degree count, XCD-localized ----------------
// block b: edge chunk b>>3, commits only dst in node-range (b&7) -> atomics stay
// in one XCD's L2 (round-robin dispatch heuristic; correctness mapping-independent).
__global__ __launch_bounds__(256) void k_deg(const int* __restrict__ ei, int E,
                                             int* __restrict__ deg, int nper) {
    int b = blockIdx.x;
    int i = (b >> 3) * 256 + threadIdx.x;
    if (i >= E) return;
    int d = ei[E + i];
    int lo = (b & 7) * nper;
    if (d >= lo && d < lo + nper) atomicAdd(&deg[d], 1);
}

// ---------------- 3-kernel deterministic exclusive scan over deg ----------------
__global__ __launch_bounds__(256) void k_scanA(const int* __restrict__ deg, int N,
                                               int* __restrict__ bsum) {
    __shared__ int red[256];
    int tid = threadIdx.x;
    int i = blockIdx.x * 256 + tid;
    int v = (i < N) ? deg[i] : 0;
    red[tid] = v; __syncthreads();
    for (int s = 128; s > 0; s >>= 1) {
        if (tid < s) red[tid] += red[tid + s];
        __syncthreads();
    }
    if (tid == 0) bsum[blockIdx.x] = red[0];
}

__global__ __launch_bounds__(256) void k_scanB(const int* __restrict__ bsum, int NB,
                                               int* __restrict__ bbase) {
    __shared__ int sc[256];
    int tid = threadIdx.x;
    int v = (tid < NB) ? bsum[tid] : 0;
    sc[tid] = v; __syncthreads();
    for (int s = 1; s < 256; s <<= 1) {
        int t = (tid >= s) ? sc[tid - s] : 0;
        __syncthreads();
        sc[tid] += t;
        __syncthreads();
    }
    bbase[tid] = sc[tid] - v;   // exclusive
}

__global__ __launch_bounds__(256) void k_scanC(const int* __restrict__ deg, int N,
                                               const int* __restrict__ bbase,
                                               int* __restrict__ offs) {
    __shared__ int sc[256];
    int tid = threadIdx.x;
    int i = blockIdx.x * 256 + tid;
    int v = (i < N) ? deg[i] : 0;
    sc[tid] = v; __syncthreads();
    for (int s = 1; s < 256; s <<= 1) {
        int t = (tid >= s) ? sc[tid - s] : 0;
        __syncthreads();
        sc[tid] += t;
        __syncthreads();
    }
    if (i < N) {
        offs[i] = bbase[blockIdx.x] + sc[tid] - v;
        if (i == N - 1) offs[N] = bbase[blockIdx.x] + sc[tid];   // sentinel = E
    }
}

// ---------------- CSR fill (u16 src), XCD-localized like k_deg ----------------
__global__ __launch_bounds__(256) void k_fill(const int* __restrict__ ei, int E,
                                              const int* __restrict__ offs,
                                              int* __restrict__ cursor,
                                              unsigned short* __restrict__ csr,
                                              int nper) {
    int b = blockIdx.x;
    int i = (b >> 3) * 256 + threadIdx.x;
    if (i >= E) return;
    int d = ei[E + i];
    int lo = (b & 7) * nper;
    if (d >= lo && d < lo + nper) {
        int p = atomicAdd(&cursor[d], 1);
        csr[offs[d] + p] = (unsigned short)ei[i];
    }
}

// ---------------- weight prep -> bf16 MFMA B-layout ----------------
// Per layer: wt[8 ks][128 col][32 k] bf16; entry = W[col][ks*32+k].
// mats: 0=W1l(L0 half0), 1=W1r(L0 half1), 2=W2l(L1 half0).
__global__ __launch_bounds__(256) void k_prep_w(const float* __restrict__ w0,
                                                const float* __restrict__ w1,
                                                const float* __restrict__ w2,
                                                unsigned short* __restrict__ wt) {
    int t = blockIdx.x * 256 + threadIdx.x;     // 0..6143
    if (t >= 6144) return;
    int mat = t >> 11, rem = t & 2047;
    int col = rem >> 4, ks = (rem >> 2) & 3, qq = rem & 3;
    const float* W = (mat == 0) ? w0 : (mat == 1) ? w1 : w2;
    int layer = (mat == 2) ? 1 : 0, half = (mat == 1) ? 1 : 0;
    const float* src = W + col * NF + ks * 32 + qq * 8;
    u16x8 d;
#pragma unroll
    for (int j = 0; j < 8; ++j) d[j] = f2b(src[j]);
    *(u16x8*)(wt + layer * 65536 + (half * 4 + ks) * 4096 + col * 32 + qq * 8) = d;
}

// ---------------- layer-2 lin_r weight: fold BN scale/shift exactly ----------------
__global__ __launch_bounds__(256) void k_prep_w2(const float* __restrict__ w2r,
                                                 const float* __restrict__ sbn,
                                                 const float* __restrict__ b2l,
                                                 const float* __restrict__ bbn,
                                                 unsigned short* __restrict__ wtL2,
                                                 float* __restrict__ bias2) {
    if (blockIdx.x < 8) {
        int t = blockIdx.x * 256 + threadIdx.x;  // 0..2047
        int col = t >> 4, ks = (t >> 2) & 3, qq = t & 3;
        int k0 = ks * 32 + qq * 8;
        u16x8 d;
#pragma unroll
        for (int j = 0; j < 8; ++j) d[j] = f2b(w2r[col * NF + k0 + j] * sbn[k0 + j]);
        *(u16x8*)(wtL2 + (4 + ks) * 4096 + col * 32 + qq * 8) = d;
    } else {
        int f = threadIdx.x;
        if (f < NF) {
            float s = b2l[f];
            for (int k = 0; k < NF; ++k) s += w2r[f * NF + k] * bbn[k];
            bias2[f] = s;
        }
    }
}

// ---------------- aggregate, XCD-sliced ----------------
template <bool TR>
__global__ __launch_bounds__(256) void k_agg(const unsigned* __restrict__ tab,  // [4][N][16] u32
                                             const unsigned short* __restrict__ csr,
                                             const int* __restrict__ offs,
                                             const float* __restrict__ sbn,
                                             const float* __restrict__ bbn,
                                             unsigned* __restrict__ outT, int N) {
    int b = blockIdx.x;
    int s = (b & 7) >> 1;
    int chunk = (b >> 3) * 2 + (b & 1);
    int tid = threadIdx.x;
    int wid = tid >> 6, lane = tid & 63, g = lane >> 4, li = lane & 15;
    int node = chunk * 16 + wid * 4 + g;
    if (node >= N) return;
    int beg = offs[node], cnt = offs[node + 1] - beg;
    const unsigned* T = tab + (size_t)s * N * 16;
    float ax0 = 0, ay0 = 0, ax1 = 0, ay1 = 0;
    int j = 0;
    for (; j + 4 <= cnt; j += 4) {
        int s0 = csr[beg + j + 0], s1 = csr[beg + j + 1];
        int s2 = csr[beg + j + 2], s3 = csr[beg + j + 3];
        unsigned v0 = T[(size_t)s0 * 16 + li];
        unsigned v1 = T[(size_t)s1 * 16 + li];
        unsigned v2 = T[(size_t)s2 * 16 + li];
        unsigned v3 = T[(size_t)s3 * 16 + li];
        ax0 += blo(v0) + blo(v2); ay0 += bhi(v0) + bhi(v2);
        ax1 += blo(v1) + blo(v3); ay1 += bhi(v1) + bhi(v3);
    }
    for (; j < cnt; ++j) {
        unsigned v = T[(size_t)csr[beg + j] * 16 + li];
        ax0 += blo(v); ay0 += bhi(v);
    }
    float id = (cnt > 0) ? 1.0f / (float)cnt : 0.f;
    float rx = (ax0 + ax1) * id;
    float ry = (ay0 + ay1) * id;
    if (TR) {
        if (cnt > 0) {
            float2 sc = ((const float2*)sbn)[s * 16 + li];
            float2 bc = ((const float2*)bbn)[s * 16 + li];
            rx = rx * sc.x + bc.x;
            ry = ry * sc.y + bc.y;
        }
    }
    outT[(size_t)s * N * 16 + (size_t)node * 16 + li] =
        (unsigned)f2b(rx) | ((unsigned)f2b(ry) << 16);
}

// ---------------- MFMA linear (+bias +L2norm), LDS-staged weights ----------------
// 64 rows/block, 4 waves; wave = 16 rows x 128 cols = 8 ks x 8 c mfma_16x16x32_bf16.
// Weights (64KB) staged to LDS once per block -> main loop is ds_read_b128 + MFMA
// (tile read = 2 lanes/bank, conflict-free). LDS 68KB -> 2 blocks/CU.
// C layout: col = lane&15, row = (lane>>4)*4 + reg [m89].
template <int MODE>
__global__ __launch_bounds__(256, 2) void k_lin(
    const unsigned short* __restrict__ aggB,   // sliced [4][N][32] bf16
    const unsigned short* __restrict__ src2,   // sliced [4][N][32] bf16 (xb / h1b)
    const unsigned short* __restrict__ wt,     // layer base: [8][128][32] bf16
    const float* __restrict__ bias,            // [128] (layer2: BN-folded)
    const float* __restrict__ wfc, const float* __restrict__ bfc,   // MODE2
    unsigned short* __restrict__ outb,         // MODE1: h1b sliced [4][N][32]
    float* __restrict__ outf,                  // MODE2: out [N,8]
    float* __restrict__ bnSum, float* __restrict__ bnSq, int N) {
    __shared__ __align__(16) unsigned short wlds[32768];   // 64 KB
    __shared__ float sbuf[1024];                           // 4 KB

    int tid = threadIdx.x;
    int lane = tid & 63;
    int q = lane >> 4, m = lane & 15;
    int row_base = blockIdx.x * 64 + (tid >> 6) * 16;

    // A-frag loads issued first (HBM latency hides under LDS staging)
    int r = row_base + m; if (r >= N) r = N - 1;           // clamp (outputs guarded)
    size_t rr = (size_t)r * 32 + q * 8;
    s16x8 afr[8];
#pragma unroll
    for (int ks = 0; ks < 4; ++ks) afr[ks] = *(const s16x8*)(aggB + (size_t)ks * N * 32 + rr);
#pragma unroll
    for (int ks = 0; ks < 4; ++ks) afr[4 + ks] = *(const s16x8*)(src2 + (size_t)ks * N * 32 + rr);

    // stage weights: 4096 f4 = 64 KB, 16 per thread
    {
        const f4* wsrc4 = (const f4*)wt;
        f4* wd4 = (f4*)wlds;
#pragma unroll
        for (int it = 0; it < 16; ++it) wd4[tid + it * 256] = wsrc4[tid + it * 256];
    }
    if constexpr (MODE == 1) {
        if (tid < 256) sbuf[tid] = 0.f;
    } else {
        *(f4*)&sbuf[tid * 4] = ((const f4*)wfc)[tid];      // 1024 floats
    }
    __syncthreads();

    f4 acc[8];
#pragma unroll
    for (int c = 0; c < 8; ++c) acc[c] = (f4){0.f, 0.f, 0.f, 0.f};

    const unsigned short* wb = wlds + m * 32 + q * 8;
#pragma unroll
    for (int ks = 0; ks < 8; ++ks) {
#pragma unroll
        for (int c = 0; c < 8; ++c) {
            s16x8 bfr = *(const s16x8*)(wb + ks * 4096 + c * 512);
            acc[c] = __builtin_amdgcn_mfma_f32_16x16x32_bf16(afr[ks], bfr, acc[c], 0, 0, 0);
        }
    }

    // bias (col = c*16+m)
#pragma unroll
    for (int c = 0; c < 8; ++c) {
        float b = bias[c * 16 + m];
#pragma unroll
        for (int i = 0; i < 4; ++i) acc[c][i] += b;
    }
    // row L2 norm: row = row_base + q*4 + i lives in the 16 lanes of this q-group
    float ss[4];
#pragma unroll
    for (int i = 0; i < 4; ++i) {
        float s = 0.f;
#pragma unroll
        for (int c = 0; c < 8; ++c) s += acc[c][i] * acc[c][i];
        s += __shfl_xor(s, 1); s += __shfl_xor(s, 2);
        s += __shfl_xor(s, 4); s += __shfl_xor(s, 8);
        ss[i] = 1.0f / fmaxf(sqrtf(s), 1e-12f);
    }
#pragma unroll
    for (int c = 0; c < 8; ++c)
#pragma unroll
        for (int i = 0; i < 4; ++i) acc[c][i] *= ss[i];

    if constexpr (MODE == 1) {
        // relu
#pragma unroll
        for (int c = 0; c < 8; ++c)
#pragma unroll
            for (int i = 0; i < 4; ++i) acc[c][i] = fmaxf(acc[c][i], 0.f);
        // store h1 bf16, sliced: feat c*16+m -> slice c>>1, offset (c&1)*16+m
#pragma unroll
        for (int i = 0; i < 4; ++i) {
            int row = row_base + q * 4 + i;
            if (row < N) {
#pragma unroll
                for (int c = 0; c < 8; ++c)
                    outb[(size_t)(c >> 1) * N * 32 + (size_t)row * 32 + (c & 1) * 16 + m] =
                        f2b(acc[c][i]);
            }
        }
        // BN partial sums per col over this wave's 16 rows
        float su[8], sq[8];
#pragma unroll
        for (int c = 0; c < 8; ++c) { su[c] = 0.f; sq[c] = 0.f; }
#pragma unroll
        for (int i = 0; i < 4; ++i) {
            bool vi = (row_base + q * 4 + i) < N;
#pragma unroll
            for (int c = 0; c < 8; ++c) {
                float u = vi ? acc[c][i] : 0.f;
                su[c] += u; sq[c] += u * u;
            }
        }
#pragma unroll
        for (int c = 0; c < 8; ++c) {
            su[c] += __shfl_xor(su[c], 16); su[c] += __shfl_xor(su[c], 32);
            sq[c] += __shfl_xor(sq[c], 16); sq[c] += __shfl_xor(sq[c], 32);
        }
        if (lane < 16) {
#pragma unroll
            for (int c = 0; c < 8; ++c) {
                atomicAdd(&sbuf[c * 16 + m], su[c]);
                atomicAdd(&sbuf[128 + c * 16 + m], sq[c]);
            }
        }
        __syncthreads();
        int shard = (blockIdx.x & 7) * 128;
        if (tid < 128)      atomicAdd(&bnSum[shard + tid], sbuf[tid]);
        else if (tid < 256) atomicAdd(&bnSq[shard + tid - 128], sbuf[tid]);
    } else {
        // fused FC head: out[row][cls] = sum_col h2[row][col]*wfc[cls][col] + bfc
        float o[8][4];
#pragma unroll
        for (int cls = 0; cls < 8; ++cls)
#pragma unroll
            for (int i = 0; i < 4; ++i) o[cls][i] = 0.f;
#pragma unroll
        for (int cls = 0; cls < 8; ++cls) {
#pragma unroll
            for (int c = 0; c < 8; ++c) {
                float wv = sbuf[cls * NF + c * 16 + m];
#pragma unroll
                for (int i = 0; i < 4; ++i) o[cls][i] += acc[c][i] * wv;
            }
#pragma unroll
            for (int i = 0; i < 4; ++i) {
                float t = o[cls][i];
                t += __shfl_xor(t, 1); t += __shfl_xor(t, 2);
                t += __shfl_xor(t, 4); t += __shfl_xor(t, 8);
                o[cls][i] = t;
            }
        }
        float sel[4] = {0.f, 0.f, 0.f, 0.f};
#pragma unroll
        for (int cls = 0; cls < 8; ++cls) {
            bool p = (m == cls);
#pragma unroll
            for (int i = 0; i < 4; ++i) sel[i] = p ? o[cls][i] : sel[i];
        }
        if (m < 8) {
            float bb = bfc[m];
#pragma unroll
            for (int i = 0; i < 4; ++i) {
                int row = row_base + q * 4 + i;
                if (row < N) outf[(size_t)row * 8 + m] = sel[i] + bb;
            }
        }
    }
}

// ---------------- BN finalize: sum shards, fold to scale/shift ----------------
__global__ void k_bnfin(const float* __restrict__ bnSum, const float* __restrict__ bnSq,
                        const float* __restrict__ gamma, const float* __restrict__ beta,
                        float* __restrict__ sbn, float* __restrict__ bbn, float n) {
    int f = threadIdx.x;
    float su = 0.f, sq = 0.f;
#pragma unroll
    for (int s = 0; s < 8; ++s) { su += bnSum[s * 128 + f]; sq += bnSq[s * 128 + f]; }
    float mu = su / n;
    float var = sq / n - mu * mu;
    var = fmaxf(var, 0.f);
    float s = gamma[f] / sqrtf(var + 1e-5f);
    sbn[f] = s;
    bbn[f] = beta[f] - mu * s;
}

extern "C" void kernel_launch(void* const* d_in, const int* in_sizes, int n_in,
                              void* d_out, int out_size, void* d_ws, size_t ws_size,
                              hipStream_t stream) {
    const float* x   = (const float*)d_in[0];
    const int*   ei  = (const int*)d_in[1];
    const float* W1l = (const float*)d_in[2];
    const float* b1l = (const float*)d_in[3];
    const float* W1r = (const float*)d_in[4];
    const float* gam = (const float*)d_in[5];
    const float* bet = (const float*)d_in[6];
    const float* W2l = (const float*)d_in[7];
    const float* b2l = (const float*)d_in[8];
    const float* W2r = (const float*)d_in[9];
    const float* Wfc = (const float*)d_in[10];
    const float* bfc = (const float*)d_in[11];
    int N = in_sizes[0] / NF;
    int E = in_sizes[1] / 2;

    char* w = (char*)d_ws;
    size_t o = 0;
#define ALO(nbytes) (o = (o + 255) & ~(size_t)255, o += (nbytes), (w + o - (nbytes)))
    int* deg    = (int*)ALO((size_t)N * 4);
    int* cursor = (int*)ALO((size_t)N * 4);
    float* bnSum = (float*)ALO(4096);          // 8 shards x 128
    float* bnSq  = (float*)ALO(4096);
    size_t zwords = o / 4;                     // zero region: deg, cursor, bn shards
    int* offs  = (int*)ALO((size_t)(N + 1) * 4);
    int* bsum  = (int*)ALO(1024);
    int* bbase = (int*)ALO(1024);
    unsigned short* csr = (unsigned short*)ALO((size_t)E * 2);
    unsigned short* wt  = (unsigned short*)ALO((size_t)2 * 65536 * 2);
    float* sbn   = (float*)ALO(512);
    float* bbn   = (float*)ALO(512);
    float* bias2 = (float*)ALO(512);
    unsigned short* xb   = (unsigned short*)ALO((size_t)N * NF * 2);  // sliced [4][N][32]
    unsigned short* aggB = (unsigned short*)ALO((size_t)N * NF * 2);  // sliced
    unsigned short* h1b  = (unsigned short*)ALO((size_t)N * NF * 2);  // sliced
#undef ALO
    (void)ws_size; (void)n_in; (void)out_size;

    int NB = (N + 255) / 256;
    int EB8 = ((E + 255) / 256) * 8;
    int nper = (N + 7) / 8;
    int aggBlocks = ((N + 31) / 32) * 8;
    int LB = (N + 63) / 64;
    int CV = (N * 64 + 255) / 256;

    k_zero<<<(int)((zwords + 255) / 256), 256, 0, stream>>>((int*)d_ws, (int)zwords);
    k_deg<<<EB8, 256, 0, stream>>>(ei, E, deg, nper);
    k_cvt<<<CV, 256, 0, stream>>>(x, (unsigned*)xb, N);
    k_prep_w<<<24, 256, 0, stream>>>(W1l, W1r, W2l, wt);
    k_scanA<<<NB, 256, 0, stream>>>(deg, N, bsum);
    k_scanB<<<1, 256, 0, stream>>>(bsum, NB, bbase);
    k_scanC<<<NB, 256, 0, stream>>>(deg, N, bbase, offs);
    k_fill<<<EB8, 256, 0, stream>>>(ei, E, offs, cursor, csr, nper);

    // layer 1
    k_agg<false><<<aggBlocks, 256, 0, stream>>>((const unsigned*)xb, csr, offs,
                                                nullptr, nullptr, (unsigned*)aggB, N);
    k_lin<1><<<LB, 256, 0, stream>>>(aggB, xb, wt, b1l, nullptr, nullptr,
                                     h1b, nullptr, bnSum, bnSq, N);
    k_bnfin<<<1, 128, 0, stream>>>(bnSum, bnSq, gam, bet, sbn, bbn, (float)N);
    k_prep_w2<<<9, 256, 0, stream>>>(W2r, sbn, b2l, bbn, wt + 65536, bias2);
    // layer 2 (BN folded: agg epilogue for lin_l, weights for lin_r) + fused FC head
    k_agg<true><<<aggBlocks, 256, 0, stream>>>((const unsigned*)h1b, csr, offs,
                                               sbn, bbn, (unsigned*)aggB, N);
    k_lin<2><<<LB, 256, 0, stream>>>(aggB, h1b, wt + 65536, bias2, Wfc, bfc,
                                     nullptr, (float*)d_out, nullptr, nullptr, N);
}

// Round 8
// 201.875 us; speedup vs baseline: 1.9110x; 1.0696x over previous
//
#include <hip/hip_runtime.h>
#include <hip/hip_bf16.h>

#define NF 128

typedef float f4 __attribute__((ext_vector_type(4)));
typedef short s16x8 __attribute__((ext_vector_type(8)));
typedef unsigned short u16x8 __attribute__((ext_vector_type(8)));

static __device__ __forceinline__ unsigned short f2b(float f) {
    union { float f; unsigned u; } c; c.f = f;
    unsigned r = c.u + 0x7fffu + ((c.u >> 16) & 1u);
    return (unsigned short)(r >> 16);
}
static __device__ __forceinline__ float blo(unsigned v) { return __uint_as_float(v << 16); }
static __device__ __forceinline__ float bhi(unsigned v) { return __uint_as_float(v & 0xffff0000u); }

// ---------------- zero scratch ----------------
__global__ __launch_bounds__(256) void k_zero(int* __restrict__ p, int nwords) {
    int i = blockIdx.x * 256 + threadIdx.x;
    if (i < nwords) p[i] = 0;
}

// ---------------- x -> bf16, XCD-sliced layout [4][N][32 feats] (u32 = 2 feats) ----
__global__ __launch_bounds__(256) void k_cvt(const float* __restrict__ x,
                                             unsigned* __restrict__ out32, int N) {
    int i = blockIdx.x * 256 + threadIdx.x;
    if (i >= N * 64) return;
    int n = i >> 6, l = i & 63;          // l = feature-pair 0..63
    int s = l >> 4, li = l & 15;         // slice, pair-within-slice
    float2 v = *(const float2*)(x + (size_t)n * NF + l * 2);
    out32[(size_t)s * N * 16 + (size_t)n * 16 + li] =
        (unsigned)f2b(v.x) | ((unsigned)f2b(v.y) << 16);
}

// ---------------- degree count, XCD-localized ----------------
__global__ __launch_bounds__(256) void k_deg(const int* __restrict__ ei, int E,
                                             int* __restrict__ deg, int nper) {
    int b = blockIdx.x;
    int i = (b >> 3) * 256 + threadIdx.x;
    if (i >= E) return;
    int d = ei[E + i];
    int lo = (b & 7) * nper;
    if (d >= lo && d < lo + nper) atomicAdd(&deg[d], 1);
}

// ---------------- 3-kernel deterministic exclusive scan over deg ----------------
__global__ __launch_bounds__(256) void k_scanA(const int* __restrict__ deg, int N,
                                               int* __restrict__ bsum) {
    __shared__ int red[256];
    int tid = threadIdx.x;
    int i = blockIdx.x * 256 + tid;
    int v = (i < N) ? deg[i] : 0;
    red[tid] = v; __syncthreads();
    for (int s = 128; s > 0; s >>= 1) {
        if (tid < s) red[tid] += red[tid + s];
        __syncthreads();
    }
    if (tid == 0) bsum[blockIdx.x] = red[0];
}

__global__ __launch_bounds__(256) void k_scanB(const int* __restrict__ bsum, int NB,
                                               int* __restrict__ bbase) {
    __shared__ int sc[256];
    int tid = threadIdx.x;
    int v = (tid < NB) ? bsum[tid] : 0;
    sc[tid] = v; __syncthreads();
    for (int s = 1; s < 256; s <<= 1) {
        int t = (tid >= s) ? sc[tid - s] : 0;
        __syncthreads();
        sc[tid] += t;
        __syncthreads();
    }
    bbase[tid] = sc[tid] - v;   // exclusive
}

__global__ __launch_bounds__(256) void k_scanC(const int* __restrict__ deg, int N,
                                               const int* __restrict__ bbase,
                                               int* __restrict__ offs) {
    __shared__ int sc[256];
    int tid = threadIdx.x;
    int i = blockIdx.x * 256 + tid;
    int v = (i < N) ? deg[i] : 0;
    sc[tid] = v; __syncthreads();
    for (int s = 1; s < 256; s <<= 1) {
        int t = (tid >= s) ? sc[tid - s] : 0;
        __syncthreads();
        sc[tid] += t;
        __syncthreads();
    }
    if (i < N) {
        offs[i] = bbase[blockIdx.x] + sc[tid] - v;
        if (i == N - 1) offs[N] = bbase[blockIdx.x] + sc[tid];   // sentinel = E
    }
}

// ---------------- CSR fill (u16 src), XCD-localized like k_deg ----------------
__global__ __launch_bounds__(256) void k_fill(const int* __restrict__ ei, int E,
                                              const int* __restrict__ offs,
                                              int* __restrict__ cursor,
                                              unsigned short* __restrict__ csr,
                                              int nper) {
    int b = blockIdx.x;
    int i = (b >> 3) * 256 + threadIdx.x;
    if (i >= E) return;
    int d = ei[E + i];
    int lo = (b & 7) * nper;
    if (d >= lo && d < lo + nper) {
        int p = atomicAdd(&cursor[d], 1);
        csr[offs[d] + p] = (unsigned short)ei[i];
    }
}

// ---------------- weight prep -> bf16 MFMA B-layout, lane-contiguous ----------------
// Per layer (65536 u16): idx = ks*4096 + (col>>4)*512 + ((kq*16 + (col&15))*8 + kk
// so MFMA lane l=(kq*16+m) reads bytes l*16 of each (ks,c) 1KB sub-block: LDS reads
// are a contiguous 1KB span per wave -> 2 lanes/bank, conflict-free.
// mats: 0=W1l(L0 half0), 1=W1r(L0 half1), 2=W2l(L1 half0).
__global__ __launch_bounds__(256) void k_prep_w(const float* __restrict__ w0,
                                                const float* __restrict__ w1,
                                                const float* __restrict__ w2,
                                                unsigned short* __restrict__ wt) {
    int t = blockIdx.x * 256 + threadIdx.x;     // 0..6143
    if (t >= 6144) return;
    int mat = t >> 11, rem = t & 2047;
    int col = rem >> 4, ks = (rem >> 2) & 3, qq = rem & 3;
    const float* W = (mat == 0) ? w0 : (mat == 1) ? w1 : w2;
    int layer = (mat == 2) ? 1 : 0, half = (mat == 1) ? 1 : 0;
    const float* src = W + col * NF + ks * 32 + qq * 8;
    u16x8 d;
#pragma unroll
    for (int j = 0; j < 8; ++j) d[j] = f2b(src[j]);
    *(u16x8*)(wt + layer * 65536 + (half * 4 + ks) * 4096 + (col >> 4) * 512 +
              (qq * 16 + (col & 15)) * 8) = d;
}

// ---------------- layer-2 lin_r weight: fold BN scale/shift exactly ----------------
__global__ __launch_bounds__(256) void k_prep_w2(const float* __restrict__ w2r,
                                                 const float* __restrict__ sbn,
                                                 const float* __restrict__ b2l,
                                                 const float* __restrict__ bbn,
                                                 unsigned short* __restrict__ wtL2,
                                                 float* __restrict__ bias2) {
    if (blockIdx.x < 8) {
        int t = blockIdx.x * 256 + threadIdx.x;  // 0..2047
        int col = t >> 4, ks = (t >> 2) & 3, qq = t & 3;
        int k0 = ks * 32 + qq * 8;
        u16x8 d;
#pragma unroll
        for (int j = 0; j < 8; ++j) d[j] = f2b(w2r[col * NF + k0 + j] * sbn[k0 + j]);
        *(u16x8*)(wtL2 + (4 + ks) * 4096 + (col >> 4) * 512 +
                  (qq * 16 + (col & 15)) * 8) = d;
    } else {
        int f = threadIdx.x;
        if (f < NF) {
            float s = b2l[f];
            for (int k = 0; k < NF; ++k) s += w2r[f * NF + k] * bbn[k];
            bias2[f] = s;
        }
    }
}

// ---------------- aggregate, XCD-sliced, uint4 gathers ----------------
// 16-lane group per node: nb=li>>2 (neighbor in quad), fq=li&3 (16B of the 64B row).
// One uint4 load fetches 4 neighbors per group; reduce across nb via shfl_xor(4,8).
template <bool TR>
__global__ __launch_bounds__(256) void k_agg(const uint4* __restrict__ T4all, // [4][N][4]
                                             const unsigned short* __restrict__ csr,
                                             const int* __restrict__ offs,
                                             const float* __restrict__ sbn,
                                             const float* __restrict__ bbn,
                                             uint4* __restrict__ outT4, int N) {
    int b = blockIdx.x;
    int s = (b & 7) >> 1;
    int chunk = (b >> 3) * 2 + (b & 1);
    int tid = threadIdx.x;
    int wid = tid >> 6, lane = tid & 63, g = lane >> 4, li = lane & 15;
    int node = chunk * 16 + wid * 4 + g;
    if (node >= N) return;
    int beg = offs[node], cnt = offs[node + 1] - beg;
    int nb = li >> 2, fq = li & 3;
    const uint4* T4 = T4all + (size_t)s * N * 4;
    const unsigned short* cp = csr + beg;
    float a0 = 0, a1 = 0, a2 = 0, a3 = 0, a4 = 0, a5 = 0, a6 = 0, a7 = 0;
    int j = 0;
    for (; j + 8 <= cnt; j += 8) {
        int sA = cp[j + nb], sB = cp[j + 4 + nb];
        uint4 vA = T4[(size_t)sA * 4 + fq];
        uint4 vB = T4[(size_t)sB * 4 + fq];
        a0 += blo(vA.x) + blo(vB.x); a1 += bhi(vA.x) + bhi(vB.x);
        a2 += blo(vA.y) + blo(vB.y); a3 += bhi(vA.y) + bhi(vB.y);
        a4 += blo(vA.z) + blo(vB.z); a5 += bhi(vA.z) + bhi(vB.z);
        a6 += blo(vA.w) + blo(vB.w); a7 += bhi(vA.w) + bhi(vB.w);
    }
    for (; j < cnt; j += 4) {
        int idx = j + nb;
        bool val = idx < cnt;
        int sA = cp[val ? idx : j];
        uint4 vA = T4[(size_t)sA * 4 + fq];
        if (val) {
            a0 += blo(vA.x); a1 += bhi(vA.x);
            a2 += blo(vA.y); a3 += bhi(vA.y);
            a4 += blo(vA.z); a5 += bhi(vA.z);
            a6 += blo(vA.w); a7 += bhi(vA.w);
        }
    }
    a0 += __shfl_xor(a0, 4); a1 += __shfl_xor(a1, 4);
    a2 += __shfl_xor(a2, 4); a3 += __shfl_xor(a3, 4);
    a4 += __shfl_xor(a4, 4); a5 += __shfl_xor(a5, 4);
    a6 += __shfl_xor(a6, 4); a7 += __shfl_xor(a7, 4);
    a0 += __shfl_xor(a0, 8); a1 += __shfl_xor(a1, 8);
    a2 += __shfl_xor(a2, 8); a3 += __shfl_xor(a3, 8);
    a4 += __shfl_xor(a4, 8); a5 += __shfl_xor(a5, 8);
    a6 += __shfl_xor(a6, 8); a7 += __shfl_xor(a7, 8);
    if (li < 4) {
        float id = (cnt > 0) ? 1.0f / (float)cnt : 0.f;
        float r[8] = {a0 * id, a1 * id, a2 * id, a3 * id,
                      a4 * id, a5 * id, a6 * id, a7 * id};
        if (TR) {
            if (cnt > 0) {   // mean(s*v+b) = s*mean(v)+b when deg>0, else 0
                const float2* sc2 = (const float2*)(sbn + s * 32 + fq * 8);
                const float2* bc2 = (const float2*)(bbn + s * 32 + fq * 8);
#pragma unroll
                for (int i = 0; i < 4; ++i) {
                    float2 sc = sc2[i], bc = bc2[i];
                    r[2 * i]     = r[2 * i]     * sc.x + bc.x;
                    r[2 * i + 1] = r[2 * i + 1] * sc.y + bc.y;
                }
            }
        }
        uint4 p;
        p.x = (unsigned)f2b(r[0]) | ((unsigned)f2b(r[1]) << 16);
        p.y = (unsigned)f2b(r[2]) | ((unsigned)f2b(r[3]) << 16);
        p.z = (unsigned)f2b(r[4]) | ((unsigned)f2b(r[5]) << 16);
        p.w = (unsigned)f2b(r[6]) | ((unsigned)f2b(r[7]) << 16);
        outT4[((size_t)s * N + node) * 4 + fq] = p;
    }
}

// ---------------- MFMA linear (+bias +L2norm), LDS-staged weights ----------------
// 64 rows/block, 4 waves; wave = 16 rows x 128 cols = 8 ks x 8 c mfma_16x16x32_bf16.
// Weights (64KB) staged to LDS once; lane-contiguous layout -> each B-frag read is
// part of a contiguous 1KB wave-span (2 lanes/bank, conflict-free).
// C layout: col = lane&15, row = (lane>>4)*4 + reg [m89].
template <int MODE>
__global__ __launch_bounds__(256, 2) void k_lin(
    const unsigned short* __restrict__ aggB,   // sliced [4][N][32] bf16
    const unsigned short* __restrict__ src2,   // sliced [4][N][32] bf16 (xb / h1b)
    const unsigned short* __restrict__ wt,     // layer base: lane-contiguous layout
    const float* __restrict__ bias,            // [128] (layer2: BN-folded)
    const float* __restrict__ wfc, const float* __restrict__ bfc,   // MODE2
    unsigned short* __restrict__ outb,         // MODE1: h1b sliced [4][N][32]
    float* __restrict__ outf,                  // MODE2: out [N,8]
    float* __restrict__ bnSum, float* __restrict__ bnSq, int N) {
    __shared__ __align__(16) unsigned short wlds[32768];   // 64 KB
    __shared__ float sbuf[1024];                           // 4 KB

    int tid = threadIdx.x;
    int lane = tid & 63;
    int q = lane >> 4, m = lane & 15;
    int row_base = blockIdx.x * 64 + (tid >> 6) * 16;

    // A-frag loads issued first (HBM latency hides under LDS staging)
    int r = row_base + m; if (r >= N) r = N - 1;           // clamp (outputs guarded)
    size_t rr = (size_t)r * 32 + q * 8;
    s16x8 afr[8];
#pragma unroll
    for (int ks = 0; ks < 4; ++ks) afr[ks] = *(const s16x8*)(aggB + (size_t)ks * N * 32 + rr);
#pragma unroll
    for (int ks = 0; ks < 4; ++ks) afr[4 + ks] = *(const s16x8*)(src2 + (size_t)ks * N * 32 + rr);

    // stage weights: 4096 f4 = 64 KB, 16 per thread
    {
        const f4* wsrc4 = (const f4*)wt;
        f4* wd4 = (f4*)wlds;
#pragma unroll
        for (int it = 0; it < 16; ++it) wd4[tid + it * 256] = wsrc4[tid + it * 256];
    }
    if constexpr (MODE == 1) {
        if (tid < 256) sbuf[tid] = 0.f;
    } else {
        *(f4*)&sbuf[tid * 4] = ((const f4*)wfc)[tid];      // 1024 floats
    }
    __syncthreads();

    f4 acc[8];
#pragma unroll
    for (int c = 0; c < 8; ++c) acc[c] = (f4){0.f, 0.f, 0.f, 0.f};

    const unsigned short* wb = wlds + lane * 8;            // lane-contiguous
#pragma unroll
    for (int ks = 0; ks < 8; ++ks) {
#pragma unroll
        for (int c = 0; c < 8; ++c) {
            s16x8 bfr = *(const s16x8*)(wb + ks * 4096 + c * 512);
            acc[c] = __builtin_amdgcn_mfma_f32_16x16x32_bf16(afr[ks], bfr, acc[c], 0, 0, 0);
        }
    }

    // bias (col = c*16+m)
#pragma unroll
    for (int c = 0; c < 8; ++c) {
        float b = bias[c * 16 + m];
#pragma unroll
        for (int i = 0; i < 4; ++i) acc[c][i] += b;
    }
    // row L2 norm: row = row_base + q*4 + i lives in the 16 lanes of this q-group
    float ss[4];
#pragma unroll
    for (int i = 0; i < 4; ++i) {
        float s = 0.f;
#pragma unroll
        for (int c = 0; c < 8; ++c) s += acc[c][i] * acc[c][i];
        s += __shfl_xor(s, 1); s += __shfl_xor(s, 2);
        s += __shfl_xor(s, 4); s += __shfl_xor(s, 8);
        ss[i] = 1.0f / fmaxf(sqrtf(s), 1e-12f);
    }
#pragma unroll
    for (int c = 0; c < 8; ++c)
#pragma unroll
        for (int i = 0; i < 4; ++i) acc[c][i] *= ss[i];

    if constexpr (MODE == 1) {
        // relu
#pragma unroll
        for (int c = 0; c < 8; ++c)
#pragma unroll
            for (int i = 0; i < 4; ++i) acc[c][i] = fmaxf(acc[c][i], 0.f);
        // store h1 bf16, sliced: feat c*16+m -> slice c>>1, offset (c&1)*16+m
#pragma unroll
        for (int i = 0; i < 4; ++i) {
            int row = row_base + q * 4 + i;
            if (row < N) {
#pragma unroll
                for (int c = 0; c < 8; ++c)
                    outb[(size_t)(c >> 1) * N * 32 + (size_t)row * 32 + (c & 1) * 16 + m] =
                        f2b(acc[c][i]);
            }
        }
        // BN partial sums per col over this wave's 16 rows
        float su[8], sq[8];
#pragma unroll
        for (int c = 0; c < 8; ++c) { su[c] = 0.f; sq[c] = 0.f; }
#pragma unroll
        for (int i = 0; i < 4; ++i) {
            bool vi = (row_base + q * 4 + i) < N;
#pragma unroll
            for (int c = 0; c < 8; ++c) {
                float u = vi ? acc[c][i] : 0.f;
                su[c] += u; sq[c] += u * u;
            }
        }
#pragma unroll
        for (int c = 0; c < 8; ++c) {
            su[c] += __shfl_xor(su[c], 16); su[c] += __shfl_xor(su[c], 32);
            sq[c] += __shfl_xor(sq[c], 16); sq[c] += __shfl_xor(sq[c], 32);
        }
        if (lane < 16) {
#pragma unroll
            for (int c = 0; c < 8; ++c) {
                atomicAdd(&sbuf[c * 16 + m], su[c]);
                atomicAdd(&sbuf[128 + c * 16 + m], sq[c]);
            }
        }
        __syncthreads();
        int shard = (blockIdx.x & 7) * 128;
        if (tid < 128)      atomicAdd(&bnSum[shard + tid], sbuf[tid]);
        else if (tid < 256) atomicAdd(&bnSq[shard + tid - 128], sbuf[tid]);
    } else {
        // fused FC head: out[row][cls] = sum_col h2[row][col]*wfc[cls][col] + bfc
        float o[8][4];
#pragma unroll
        for (int cls = 0; cls < 8; ++cls)
#pragma unroll
            for (int i = 0; i < 4; ++i) o[cls][i] = 0.f;
#pragma unroll
        for (int cls = 0; cls < 8; ++cls) {
#pragma unroll
            for (int c = 0; c < 8; ++c) {
                float wv = sbuf[cls * NF + c * 16 + m];
#pragma unroll
                for (int i = 0; i < 4; ++i) o[cls][i] += acc[c][i] * wv;
            }
#pragma unroll
            for (int i = 0; i < 4; ++i) {
                float t = o[cls][i];
                t += __shfl_xor(t, 1); t += __shfl_xor(t, 2);
                t += __shfl_xor(t, 4); t += __shfl_xor(t, 8);
                o[cls][i] = t;
            }
        }
        float sel[4] = {0.f, 0.f, 0.f, 0.f};
#pragma unroll
        for (int cls = 0; cls < 8; ++cls) {
            bool p = (m == cls);
#pragma unroll
            for (int i = 0; i < 4; ++i) sel[i] = p ? o[cls][i] : sel[i];
        }
        if (m < 8) {
            float bb = bfc[m];
#pragma unroll
            for (int i = 0; i < 4; ++i) {
                int row = row_base + q * 4 + i;
                if (row < N) outf[(size_t)row * 8 + m] = sel[i] + bb;
            }
        }
    }
}

// ---------------- BN finalize: sum shards, fold to scale/shift ----------------
__global__ void k_bnfin(const float* __restrict__ bnSum, const float* __restrict__ bnSq,
                        const float* __restrict__ gamma, const float* __restrict__ beta,
                        float* __restrict__ sbn, float* __restrict__ bbn, float n) {
    int f = threadIdx.x;
    float su = 0.f, sq = 0.f;
#pragma unroll
    for (int s = 0; s < 8; ++s) { su += bnSum[s * 128 + f]; sq += bnSq[s * 128 + f]; }
    float mu = su / n;
    float var = sq / n - mu * mu;
    var = fmaxf(var, 0.f);
    float s = gamma[f] / sqrtf(var + 1e-5f);
    sbn[f] = s;
    bbn[f] = beta[f] - mu * s;
}

extern "C" void kernel_launch(void* const* d_in, const int* in_sizes, int n_in,
                              void* d_out, int out_size, void* d_ws, size_t ws_size,
                              hipStream_t stream) {
    const float* x   = (const float*)d_in[0];
    const int*   ei  = (const int*)d_in[1];
    const float* W1l = (const float*)d_in[2];
    const float* b1l = (const float*)d_in[3];
    const float* W1r = (const float*)d_in[4];
    const float* gam = (const float*)d_in[5];
    const float* bet = (const float*)d_in[6];
    const float* W2l = (const float*)d_in[7];
    const float* b2l = (const float*)d_in[8];
    const float* W2r = (const float*)d_in[9];
    const float* Wfc = (const float*)d_in[10];
    const float* bfc = (const float*)d_in[11];
    int N = in_sizes[0] / NF;
    int E = in_sizes[1] / 2;

    char* w = (char*)d_ws;
    size_t o = 0;
#define ALO(nbytes) (o = (o + 255) & ~(size_t)255, o += (nbytes), (w + o - (nbytes)))
    int* deg    = (int*)ALO((size_t)N * 4);
    int* cursor = (int*)ALO((size_t)N * 4);
    float* bnSum = (float*)ALO(4096);          // 8 shards x 128
    float* bnSq  = (float*)ALO(4096);
    size_t zwords = o / 4;                     // zero region: deg, cursor, bn shards
    int* offs  = (int*)ALO((size_t)(N + 1) * 4);
    int* bsum  = (int*)ALO(1024);
    int* bbase = (int*)ALO(1024);
    unsigned short* csr = (unsigned short*)ALO((size_t)E * 2);
    unsigned short* wt  = (unsigned short*)ALO((size_t)2 * 65536 * 2);
    float* sbn   = (float*)ALO(512);
    float* bbn   = (float*)ALO(512);
    float* bias2 = (float*)ALO(512);
    unsigned short* xb   = (unsigned short*)ALO((size_t)N * NF * 2);  // sliced [4][N][32]
    unsigned short* aggB = (unsigned short*)ALO((size_t)N * NF * 2);  // sliced
    unsigned short* h1b  = (unsigned short*)ALO((size_t)N * NF * 2);  // sliced
#undef ALO
    (void)ws_size; (void)n_in; (void)out_size;

    int NB = (N + 255) / 256;
    int EB8 = ((E + 255) / 256) * 8;
    int nper = (N + 7) / 8;
    int aggBlocks = ((N + 31) / 32) * 8;
    int LB = (N + 63) / 64;
    int CV = (N * 64 + 255) / 256;

    k_zero<<<(int)((zwords + 255) / 256), 256, 0, stream>>>((int*)d_ws, (int)zwords);
    k_deg<<<EB8, 256, 0, stream>>>(ei, E, deg, nper);
    k_cvt<<<CV, 256, 0, stream>>>(x, (unsigned*)xb, N);
    k_prep_w<<<24, 256, 0, stream>>>(W1l, W1r, W2l, wt);
    k_scanA<<<NB, 256, 0, stream>>>(deg, N, bsum);
    k_scanB<<<1, 256, 0, stream>>>(bsum, NB, bbase);
    k_scanC<<<NB, 256, 0, stream>>>(deg, N, bbase, offs);
    k_fill<<<EB8, 256, 0, stream>>>(ei, E, offs, cursor, csr, nper);

    // layer 1
    k_agg<false><<<aggBlocks, 256, 0, stream>>>((const uint4*)xb, csr, offs,
                                                nullptr, nullptr, (uint4*)aggB, N);
    k_lin<1><<<LB, 256, 0, stream>>>(aggB, xb, wt, b1l, nullptr, nullptr,
                                     h1b, nullptr, bnSum, bnSq, N);
    k_bnfin<<<1, 128, 0, stream>>>(bnSum, bnSq, gam, bet, sbn, bbn, (float)N);
    k_prep_w2<<<9, 256, 0, stream>>>(W2r, sbn, b2l, bbn, wt + 65536, bias2);
    // layer 2 (BN folded: agg epilogue for lin_l, weights for lin_r) + fused FC head
    k_agg<true><<<aggBlocks, 256, 0, stream>>>((const uint4*)h1b, csr, offs,
                                               sbn, bbn, (uint4*)aggB, N);
    k_lin<2><<<LB, 256, 0, stream>>>(aggB, h1b, wt + 65536, bias2, Wfc, bfc,
                                     nullptr, (float*)d_out, nullptr, nullptr, N);
}